// Round 1
// baseline (2307.358 us; speedup 1.0000x reference)
//
#include <hip/hip_runtime.h>
#include <hip/hip_bf16.h>

// ---------------- problem constants ----------------
constexpr int B_   = 8;
constexpr int NH   = 12;
constexpr int DIM  = 768;
constexpr int HD   = 64;     // head dim
constexpr int N_   = 1025;   // 1 + 32*32
constexpr int NSP  = 1024;   // spatial tokens
constexpr int K3   = 2304;   // 3*DIM

// ---------------- workspace layout (floats) ----------------
constexpr size_t MASK_OFF = 0;                         // 8200 (padded 8448)
constexpr size_t QKV_SZ   = (size_t)B_*NH*N_*HD;       // 6,297,600
constexpr size_t Q_OFF    = 8448;
constexpr size_t K_OFF    = Q_OFF + QKV_SZ;
constexpr size_t V_OFF    = K_OFF + QKV_SZ;
constexpr size_t AO_SZ    = (size_t)B_*NSP*DIM;        // 6,291,456
constexpr size_t AO_OFF   = V_OFF + QKV_SZ;
constexpr size_t PO_OFF   = AO_OFF + AO_SZ;
// total ~126 MB

// ---------------- mask dtype detection + canonicalize ----------------
// bool bytes: nonzero bytes at i%4==1 exist (p=0.7 ones). int32 0/1: nonzero
// only at i%4==0. float32 0/1f: nonzero only at i%4 in {2,3}.
__global__ void mask_convert(const unsigned char* __restrict__ mraw,
                             float* __restrict__ mask_f, int n) {
  __shared__ int flags[2];
  int t = threadIdx.x;
  if (t < 2) flags[t] = 0;
  __syncthreads();
  int f1 = 0, f0 = 0;
  for (int i = t; i < n; i += blockDim.x) {
    unsigned char vv = mraw[i];
    if (vv) {
      int m = i & 3;
      if (m == 1) f1 = 1;
      if (m == 0) f0 = 1;
    }
  }
  if (f1) atomicOr(&flags[0], 1);
  if (f0) atomicOr(&flags[1], 1);
  __syncthreads();
  bool isBool = flags[0] != 0;
  bool isInt  = !isBool && (flags[1] != 0);
  for (int i = t; i < n; i += blockDim.x) {
    float v;
    if (isBool)     v = mraw[i] ? 1.f : 0.f;
    else if (isInt) v = ((const int*)mraw)[i] ? 1.f : 0.f;
    else            v = ((const float*)mraw)[i];
    mask_f[i] = v;
  }
}

// ---------------- fp32 tiled GEMM: 64x64 tile, BK=16, 256 thr, 4x4/thread --
// MODE 0: A=x (M=8200 rows of (b,n)), C scattered to q/k/v [b][h][n][d]
// MODE 1: A=attn_out (8192x768), C linear to o0 [row*Nc + col]
template<int MODE>
__global__ __launch_bounds__(256) void gemm_f32(
    const float* __restrict__ A, const float* __restrict__ Bw,
    const float* __restrict__ bias,
    float* __restrict__ o0, float* __restrict__ o1, float* __restrict__ o2,
    int M, int K, int Nc)
{
  __shared__ float As[16*68];   // [kk][row], pitch 68
  __shared__ float Bs[16*68];   // [kk][col], pitch 68
  const int t  = threadIdx.x;
  const int tx = t & 15, ty = t >> 4;
  const int rowBase = blockIdx.y * 64;
  const int c0      = blockIdx.x * 64;
  const int arow = t >> 2, akq = t & 3;   // A: 64 rows x 4 k-quads
  const int brow = t >> 4, bcq = t & 15;  // B: 16 krows x 16 col-quads

  float acc[4][4] = {};

  for (int k0 = 0; k0 < K; k0 += 16) {
    const int garow = rowBase + arow;
    float4 av = make_float4(0.f, 0.f, 0.f, 0.f);
    if (garow < M) av = *(const float4*)&A[(size_t)garow*K + k0 + akq*4];
    float4 bv = *(const float4*)&Bw[(size_t)(k0 + brow)*Nc + c0 + bcq*4];
    __syncthreads();                 // previous iteration's readers done
    As[(akq*4+0)*68 + arow] = av.x;
    As[(akq*4+1)*68 + arow] = av.y;
    As[(akq*4+2)*68 + arow] = av.z;
    As[(akq*4+3)*68 + arow] = av.w;
    *(float4*)&Bs[brow*68 + bcq*4] = bv;
    __syncthreads();
#pragma unroll
    for (int kk = 0; kk < 16; ++kk) {
      float4 a4 = *(float4*)&As[kk*68 + ty*4];
      float4 b4 = *(float4*)&Bs[kk*68 + tx*4];
      float ar[4] = {a4.x, a4.y, a4.z, a4.w};
      float br[4] = {b4.x, b4.y, b4.z, b4.w};
#pragma unroll
      for (int ii = 0; ii < 4; ++ii)
#pragma unroll
        for (int jj = 0; jj < 4; ++jj)
          acc[ii][jj] = fmaf(ar[ii], br[jj], acc[ii][jj]);
    }
  }

  if (MODE == 0) {
    const int c64  = c0 >> 6;          // whole 64-col block shares which/head
    const int which = c64 / NH;
    const int head  = c64 % NH;
    float* dst = (which == 0) ? o0 : (which == 1 ? o1 : o2);
    const int d = tx*4;
#pragma unroll
    for (int ii = 0; ii < 4; ++ii) {
      const int row = rowBase + ty*4 + ii;
      if (row >= M) continue;
      const int b = row / N_, n = row % N_;
      float4 val;
      val.x = acc[ii][0] + bias[c0 + d + 0];
      val.y = acc[ii][1] + bias[c0 + d + 1];
      val.z = acc[ii][2] + bias[c0 + d + 2];
      val.w = acc[ii][3] + bias[c0 + d + 3];
      *(float4*)&dst[(((size_t)(b*NH + head))*N_ + n)*HD + d] = val;
    }
  } else {
#pragma unroll
    for (int ii = 0; ii < 4; ++ii) {
      const int row = rowBase + ty*4 + ii;
      if (row >= M) continue;
      float4 val;
      val.x = acc[ii][0] + bias[c0 + tx*4 + 0];
      val.y = acc[ii][1] + bias[c0 + tx*4 + 1];
      val.z = acc[ii][2] + bias[c0 + tx*4 + 2];
      val.w = acc[ii][3] + bias[c0 + tx*4 + 3];
      *(float4*)&o0[(size_t)row*Nc + c0 + tx*4] = val;
    }
  }
}

// ---------------- fused flash attention (fp32) ----------------
// block = 256 thr = 32 q-rows x 8 lanes; 1 block per (b, head, 32-row q-tile)
// Only spatial queries (qi = 1..1024). Keys = all 1025 tokens.
__global__ __launch_bounds__(256) void attn_fused(
    const float* __restrict__ q, const float* __restrict__ k,
    const float* __restrict__ v, const float* __restrict__ mask_f,
    const float* __restrict__ rph, const float* __restrict__ rpw,
    float* __restrict__ attn_out)
{
  const int qt = blockIdx.x, head = blockIdx.y, b = blockIdx.z;
  const int t = threadIdx.x;
  const int r = t >> 3, s = t & 7;

  __shared__ float q_lds[32*68];
  __shared__ float k_lds[32*68];
  __shared__ float v_lds[32*68];
  __shared__ float bh_lds[32*33];
  __shared__ float bw_lds[32*33];
  __shared__ float p_lds[32*33];

  const int q0 = 1 + qt*32;
  const size_t bh_off = ((size_t)(b*NH + head))*N_*HD;
  const float* qb = q + bh_off;
  const float* kb = k + bh_off;
  const float* vb = v + bh_off;

  for (int it = t; it < 512; it += 256) {
    int row = it >> 4, c4 = it & 15;
    *(float4*)&q_lds[row*68 + c4*4] =
        *(const float4*)&qb[(size_t)(q0 + row)*HD + c4*4];
  }
  __syncthreads();

  // rel-pos bias tables: bh[r][kh] = q_r . Rh[hq-kh+31], bw[r][kw] likewise
  {
    const int sp = q0 + r - 1;
    const int hq = sp >> 5, wq = sp & 31;
    for (int e = s; e < 64; e += 8) {
      const float* rp = (e < 32) ? (rph + (size_t)(hq - e + 31)*HD)
                                 : (rpw + (size_t)(wq - (e - 32) + 31)*HD);
      float accd = 0.f;
#pragma unroll
      for (int c4 = 0; c4 < 16; ++c4) {
        float4 q4 = *(float4*)&q_lds[r*68 + c4*4];
        float4 r4 = *(const float4*)&rp[c4*4];
        accd += q4.x*r4.x + q4.y*r4.y + q4.z*r4.z + q4.w*r4.w;
      }
      if (e < 32) bh_lds[r*33 + e] = accd;
      else        bw_lds[r*33 + (e - 32)] = accd;
    }
  }

  const float mi = mask_f[b*N_ + q0 + r];
  const float NEG = -3.402823466e+38f;
  float m_run = NEG, l_run = 0.f;
  float acc[8];
#pragma unroll
  for (int u = 0; u < 8; ++u) acc[u] = 0.f;
  __syncthreads();   // bias tables visible to whole block

  for (int kt = 0; kt < 33; ++kt) {
    const int kbi = kt*32;
    float4 kreg[2], vreg[2];
#pragma unroll
    for (int ld = 0; ld < 2; ++ld) {
      int it = t + ld*256;
      int row = it >> 4, c4 = it & 15;
      int ki = kbi + row;
      if (ki < N_) {
        kreg[ld] = *(const float4*)&kb[(size_t)ki*HD + c4*4];
        vreg[ld] = *(const float4*)&vb[(size_t)ki*HD + c4*4];
      } else {
        kreg[ld] = make_float4(0.f,0.f,0.f,0.f);
        vreg[ld] = make_float4(0.f,0.f,0.f,0.f);
      }
    }
    __syncthreads();               // previous PV readers done
#pragma unroll
    for (int ld = 0; ld < 2; ++ld) {
      int it = t + ld*256;
      int row = it >> 4, c4 = it & 15;
      *(float4*)&k_lds[row*68 + c4*4] = kreg[ld];
      *(float4*)&v_lds[row*68 + c4*4] = vreg[ld];
    }
    __syncthreads();

    // logits for cols j0..j0+3
    const int j0 = s*4;
    float d0 = 0.f, d1 = 0.f, d2 = 0.f, d3 = 0.f;
#pragma unroll
    for (int c4 = 0; c4 < 16; ++c4) {
      float4 q4 = *(float4*)&q_lds[r*68 + c4*4];
      float4 k0v = *(float4*)&k_lds[(j0+0)*68 + c4*4];
      float4 k1v = *(float4*)&k_lds[(j0+1)*68 + c4*4];
      float4 k2v = *(float4*)&k_lds[(j0+2)*68 + c4*4];
      float4 k3v = *(float4*)&k_lds[(j0+3)*68 + c4*4];
      d0 += q4.x*k0v.x + q4.y*k0v.y + q4.z*k0v.z + q4.w*k0v.w;
      d1 += q4.x*k1v.x + q4.y*k1v.y + q4.z*k1v.z + q4.w*k1v.w;
      d2 += q4.x*k2v.x + q4.y*k2v.y + q4.z*k2v.z + q4.w*k2v.w;
      d3 += q4.x*k3v.x + q4.y*k3v.y + q4.z*k3v.z + q4.w*k3v.w;
    }
    float lg[4] = {d0, d1, d2, d3};
#pragma unroll
    for (int c = 0; c < 4; ++c) {
      const int kj = kbi + j0 + c;
      if (kj < N_) {
        const float mj = mask_f[b*N_ + kj];
        float bias = 0.f;
        if (kj >= 1) {
          const int ks = kj - 1;
          bias = bh_lds[r*33 + (ks >> 5)] + bw_lds[r*33 + (ks & 31)];
        }
        lg[c] = 0.125f*lg[c] + bias - 1e9f*(1.f - mi*mj);
      } else {
        lg[c] = NEG;
      }
    }
    float tmax = fmaxf(fmaxf(lg[0], lg[1]), fmaxf(lg[2], lg[3]));
    tmax = fmaxf(tmax, __shfl_xor(tmax, 1));
    tmax = fmaxf(tmax, __shfl_xor(tmax, 2));
    tmax = fmaxf(tmax, __shfl_xor(tmax, 4));
    const float newm = fmaxf(m_run, tmax);
    const float rf = expf(m_run - newm);
    float p[4];
    float psum = 0.f;
#pragma unroll
    for (int c = 0; c < 4; ++c) { p[c] = expf(lg[c] - newm); psum += p[c]; }
    psum += __shfl_xor(psum, 1);
    psum += __shfl_xor(psum, 2);
    psum += __shfl_xor(psum, 4);
    l_run = l_run*rf + psum;
    m_run = newm;
#pragma unroll
    for (int u = 0; u < 8; ++u) acc[u] *= rf;
#pragma unroll
    for (int c = 0; c < 4; ++c) p_lds[r*33 + j0 + c] = p[c];
    __syncthreads();
    // PV: acc[d] += sum_j p[j] * v[j][d], this thread owns d = s*8..s*8+7
#pragma unroll 8
    for (int j = 0; j < 32; ++j) {
      const float pj = p_lds[r*33 + j];
      float4 va  = *(float4*)&v_lds[j*68 + s*8];
      float4 vb4 = *(float4*)&v_lds[j*68 + s*8 + 4];
      acc[0] = fmaf(pj, va.x,  acc[0]);
      acc[1] = fmaf(pj, va.y,  acc[1]);
      acc[2] = fmaf(pj, va.z,  acc[2]);
      acc[3] = fmaf(pj, va.w,  acc[3]);
      acc[4] = fmaf(pj, vb4.x, acc[4]);
      acc[5] = fmaf(pj, vb4.y, acc[5]);
      acc[6] = fmaf(pj, vb4.z, acc[6]);
      acc[7] = fmaf(pj, vb4.w, acc[7]);
    }
    __syncthreads();
  }

  const float inv = 1.f / l_run;
  float4 o0v, o1v;
  o0v.x = acc[0]*inv; o0v.y = acc[1]*inv; o0v.z = acc[2]*inv; o0v.w = acc[3]*inv;
  o1v.x = acc[4]*inv; o1v.y = acc[5]*inv; o1v.z = acc[6]*inv; o1v.w = acc[7]*inv;
  const size_t dst = ((size_t)(b*NSP + (q0 + r - 1)))*DIM + head*HD + s*8;
  *(float4*)&attn_out[dst]     = o0v;
  *(float4*)&attn_out[dst + 4] = o1v;
}

// ---------------- masked avg + max pooling ----------------
__global__ __launch_bounds__(256) void pool_kernel(
    const float* __restrict__ proj_out, const float* __restrict__ mask_f,
    float* __restrict__ out)
{
  const int b = blockIdx.y;
  const int c = blockIdx.x * 256 + threadIdx.x;   // 0..767
  float sum = 0.f, cnt = 0.f, mx = -3.402823466e+38f;
  for (int n = 0; n < NSP; ++n) {
    const float m  = mask_f[b*N_ + 1 + n];
    const float vv = proj_out[((size_t)(b*NSP + n))*DIM + c];
    sum = fmaf(vv, m, sum);
    cnt += m;
    mx = fmaxf(mx, vv);
  }
  out[b*1536 + c]       = sum / (cnt + 1e-7f);
  out[b*1536 + 768 + c] = mx;
}

// ---------------- launch ----------------
extern "C" void kernel_launch(void* const* d_in, const int* in_sizes, int n_in,
                              void* d_out, int out_size, void* d_ws, size_t ws_size,
                              hipStream_t stream) {
  const float* x      = (const float*)d_in[0];
  const unsigned char* mraw = (const unsigned char*)d_in[1];
  const float* qkv_w  = (const float*)d_in[2];
  const float* qkv_b  = (const float*)d_in[3];
  const float* proj_w = (const float*)d_in[4];
  const float* proj_b = (const float*)d_in[5];
  const float* rph    = (const float*)d_in[6];
  const float* rpw    = (const float*)d_in[7];

  float* ws     = (float*)d_ws;
  float* mask_f = ws + MASK_OFF;
  float* qp     = ws + Q_OFF;
  float* kp     = ws + K_OFF;
  float* vp     = ws + V_OFF;
  float* ao     = ws + AO_OFF;
  float* po     = ws + PO_OFF;

  mask_convert<<<1, 256, 0, stream>>>(mraw, mask_f, B_*N_);

  // qkv = x @ qkv_w + qkv_b, scattered into q/k/v [b][h][n][d]
  gemm_f32<0><<<dim3(K3/64, (B_*N_ + 63)/64), 256, 0, stream>>>(
      x, qkv_w, qkv_b, qp, kp, vp, B_*N_, DIM, K3);

  // fused attention over spatial queries
  attn_fused<<<dim3(32, NH, B_), 256, 0, stream>>>(
      qp, kp, vp, mask_f, rph, rpw, ao);

  // proj = attn_out @ proj_w + proj_b
  gemm_f32<1><<<dim3(DIM/64, (B_*NSP)/64), 256, 0, stream>>>(
      ao, proj_w, proj_b, po, nullptr, nullptr, B_*NSP, DIM, DIM);

  pool_kernel<<<dim3(3, B_), 256, 0, stream>>>(po, mask_f, (float*)d_out);
}

// Round 2
// 489.051 us; speedup vs baseline: 4.7180x; 4.7180x over previous
//
#include <hip/hip_runtime.h>
#include <hip/hip_bf16.h>

typedef __attribute__((ext_vector_type(8))) short short8v;
typedef __attribute__((ext_vector_type(4))) float f32x4;

constexpr int B_  = 8;
constexpr int NH  = 12;
constexpr int DIM = 768;
constexpr int HD  = 64;
constexpr int N_  = 1025;
constexpr int NSP = 1024;
constexpr int K3  = 2304;
constexpr int NPAD = 1056;   // padded kv length for V^T rows (>= 1024+32, mult of 16)

// ---- workspace byte offsets (all 256-aligned) ----
constexpr size_t OFF_MASK  = 0;                                    // 8448 f32
constexpr size_t OFF_XB    = 65536;                                // x bf16 [8200][768]
constexpr size_t OFF_QKVWT = OFF_XB + (size_t)8200*768*2;          // qkv_w^T bf16 [2304][768]
constexpr size_t OFF_PROJWT= OFF_QKVWT + (size_t)K3*768*2;         // proj_w^T bf16 [768][768]
constexpr size_t OFF_Q     = OFF_PROJWT + (size_t)768*768*2;       // q bf16 [b][h][1025][64]
constexpr size_t OFF_K     = OFF_Q + (size_t)B_*NH*N_*HD*2;
constexpr size_t OFF_V     = OFF_K + (size_t)B_*NH*N_*HD*2;        // v^T bf16 [b][h][64][NPAD]
constexpr size_t V_BYTES   = (size_t)B_*NH*HD*NPAD*2;
constexpr size_t OFF_AO    = OFF_V + V_BYTES;                      // attn_out bf16 [8192][768]
constexpr size_t OFF_PO    = OFF_AO + (size_t)8192*768*2;          // proj_out f32 [8192][768]

__device__ inline float b2f(unsigned short u) {
  union { unsigned int ui; float f; } x; x.ui = ((unsigned int)u) << 16; return x.f;
}
__device__ inline unsigned short f2b(float f) {
  union { float f; unsigned int u; } x; x.f = f;
  unsigned int r = x.u + 0x7FFFu + ((x.u >> 16) & 1u);
  return (unsigned short)(r >> 16);
}

// ---------------- mask dtype detection + canonicalize ----------------
__global__ void mask_convert(const unsigned char* __restrict__ mraw,
                             float* __restrict__ mask_f, int n) {
  __shared__ int flags[2];
  int t = threadIdx.x;
  if (t < 2) flags[t] = 0;
  __syncthreads();
  int f1 = 0, f0 = 0;
  for (int i = t; i < n; i += blockDim.x) {
    unsigned char vv = mraw[i];
    if (vv) { int m = i & 3; if (m == 1) f1 = 1; if (m == 0) f0 = 1; }
  }
  if (f1) atomicOr(&flags[0], 1);
  if (f0) atomicOr(&flags[1], 1);
  __syncthreads();
  bool isBool = flags[0] != 0;
  bool isInt  = !isBool && (flags[1] != 0);
  for (int i = t; i < n; i += blockDim.x) {
    float v;
    if (isBool)     v = mraw[i] ? 1.f : 0.f;
    else if (isInt) v = ((const int*)mraw)[i] ? 1.f : 0.f;
    else            v = ((const float*)mraw)[i];
    mask_f[i] = v;
  }
}

// ---------------- f32 -> bf16 elementwise convert ----------------
__global__ __launch_bounds__(256) void cvt_f32_bf16(
    const float* __restrict__ in, unsigned short* __restrict__ out, int n4) {
  const int stride = gridDim.x * blockDim.x;
  for (int i = blockIdx.x * blockDim.x + threadIdx.x; i < n4; i += stride) {
    float4 v = *(const float4*)&in[i * 4];
    ushort4 u;
    u.x = f2b(v.x); u.y = f2b(v.y); u.z = f2b(v.z); u.w = f2b(v.w);
    *(ushort4*)&out[i * 4] = u;
  }
}

// ---------------- f32 [K][N] -> bf16 transposed [N][K] ----------------
__global__ void transpose_cvt(const float* __restrict__ in,
                              unsigned short* __restrict__ out, int K, int N) {
  __shared__ float tile[32][33];
  const int tx = threadIdx.x, ty = threadIdx.y;
  const int n = blockIdx.x * 32 + tx, k = blockIdx.y * 32 + ty;
  tile[ty][tx] = in[(size_t)k * N + n];
  __syncthreads();
  out[(size_t)(blockIdx.x * 32 + ty) * K + blockIdx.y * 32 + tx] = f2b(tile[tx][ty]);
}

// ---------------- bf16 MFMA GEMM: C = A[M][768] * BT[N][768]^T + bias ----
// 128x128 tile, BK=32, 256 thr (4 waves, each 64x64), mfma_f32_16x16x32_bf16
// MODE 0: M=8200 rows of (b,n); scatter epilogue -> q,k bf16 [b][h][n][64],
//         v^T bf16 [b][h][64][NPAD]
// MODE 1: M=8192; epilogue -> po f32 [M][768]
template<int MODE>
__global__ __launch_bounds__(256) void gemm_bf16(
    const unsigned short* __restrict__ A, const unsigned short* __restrict__ BT,
    const float* __restrict__ bias,
    unsigned short* __restrict__ qo, unsigned short* __restrict__ ko,
    unsigned short* __restrict__ vo, float* __restrict__ po, int M)
{
  constexpr int LDK = 768;
  __shared__ unsigned short As[128 * 40];
  __shared__ unsigned short Bs[128 * 40];
  const int t = threadIdx.x;
  const int l = t & 63, w = t >> 6;
  const int lg16 = l >> 4, lm16 = l & 15;
  const int wr = w >> 1, wc = w & 1;
  const int m0 = blockIdx.y * 128, n0 = blockIdx.x * 128;

  f32x4 acc[4][4];
#pragma unroll
  for (int i = 0; i < 4; ++i)
#pragma unroll
    for (int j = 0; j < 4; ++j) acc[i][j] = (f32x4){0.f, 0.f, 0.f, 0.f};

  const int srow = t >> 1, soff = (t & 1) * 16;
  const unsigned short* Aptr = A + (size_t)(m0 + srow) * LDK + soff;
  const unsigned short* Bptr = BT + (size_t)(n0 + srow) * LDK + soff;
  const bool avalid = (MODE == 0) ? (m0 + srow < M) : true;
  const short8v z8 = {0, 0, 0, 0, 0, 0, 0, 0};

  for (int k0 = 0; k0 < LDK; k0 += 32) {
    short8v a0 = z8, a1 = z8;
    if (avalid) {
      a0 = *(const short8v*)(Aptr + k0);
      a1 = *(const short8v*)(Aptr + k0 + 8);
    }
    short8v b0 = *(const short8v*)(Bptr + k0);
    short8v b1 = *(const short8v*)(Bptr + k0 + 8);
    __syncthreads();
    *(short8v*)&As[srow * 40 + soff]     = a0;
    *(short8v*)&As[srow * 40 + soff + 8] = a1;
    *(short8v*)&Bs[srow * 40 + soff]     = b0;
    *(short8v*)&Bs[srow * 40 + soff + 8] = b1;
    __syncthreads();
    short8v af[4], bf[4];
#pragma unroll
    for (int mi = 0; mi < 4; ++mi)
      af[mi] = *(short8v*)&As[(wr * 64 + mi * 16 + lm16) * 40 + lg16 * 8];
#pragma unroll
    for (int ni = 0; ni < 4; ++ni)
      bf[ni] = *(short8v*)&Bs[(wc * 64 + ni * 16 + lm16) * 40 + lg16 * 8];
#pragma unroll
    for (int mi = 0; mi < 4; ++mi)
#pragma unroll
      for (int ni = 0; ni < 4; ++ni)
        acc[mi][ni] = __builtin_amdgcn_mfma_f32_16x16x32_bf16(
            af[mi], bf[ni], acc[mi][ni], 0, 0, 0);
  }

  if (MODE == 1) {
#pragma unroll
    for (int mi = 0; mi < 4; ++mi) {
      const int row0 = m0 + wr * 64 + mi * 16 + lg16 * 4;
#pragma unroll
      for (int ni = 0; ni < 4; ++ni) {
        const int col = n0 + wc * 64 + ni * 16 + lm16;
        const float bv = bias[col];
#pragma unroll
        for (int r = 0; r < 4; ++r)
          po[(size_t)(row0 + r) * 768 + col] = acc[mi][ni][r] + bv;
      }
    }
  } else {
#pragma unroll
    for (int mi = 0; mi < 4; ++mi) {
      const int row0 = m0 + wr * 64 + mi * 16 + lg16 * 4;
#pragma unroll
      for (int ni = 0; ni < 4; ++ni) {
        const int col = n0 + wc * 64 + ni * 16 + lm16;
        const int which = col / 768;
        const int rem = col - which * 768;
        const int head = rem >> 6, d = rem & 63;
        const float bv = bias[col];
#pragma unroll
        for (int r = 0; r < 4; ++r) {
          const int grow = row0 + r;
          if (grow >= M) continue;
          const int b = grow / 1025;
          const int n = grow - b * 1025;
          const unsigned short val = f2b(acc[mi][ni][r] + bv);
          if (which == 0)
            qo[((size_t)(b * NH + head) * N_ + n) * HD + d] = val;
          else if (which == 1)
            ko[((size_t)(b * NH + head) * N_ + n) * HD + d] = val;
          else
            vo[((size_t)(b * NH + head) * HD + d) * NPAD + n] = val;
        }
      }
    }
  }
}

// ---------------- MFMA flash attention ----------------
// block = 256 = 4 waves; each wave owns a 16-row q-subtile (64 q rows/block).
// K/V fragments read directly from global (L2-resident). V is pre-transposed.
__global__ __launch_bounds__(256) void attn_mfma(
    const unsigned short* __restrict__ qp, const unsigned short* __restrict__ kp,
    const unsigned short* __restrict__ vp, const float* __restrict__ mask_f,
    const float* __restrict__ rph, const float* __restrict__ rpw,
    unsigned short* __restrict__ ao)
{
  const int qt = blockIdx.x, head = blockIdx.y, b = blockIdx.z;
  const int t = threadIdx.x, l = t & 63, w = t >> 6;
  const int lg16 = l >> 4, lm16 = l & 15;

  __shared__ float bh_lds[64][32];
  __shared__ float bw_lds[64][32];
  __shared__ unsigned short p_lds[4][16 * 40];

  const size_t bh_off = (size_t)(b * NH + head) * N_ * HD;
  const unsigned short* qb = qp + bh_off;
  const unsigned short* kb = kp + bh_off;
  const unsigned short* vb = vp + (size_t)(b * NH + head) * HD * NPAD;

  const int q0 = qt * 64 + w * 16;   // spatial base row for this wave

  // Q fragments (A operand): row = lm16, k(d) = kk*32 + lg16*8 + j
  short8v qf[2];
#pragma unroll
  for (int kk = 0; kk < 2; ++kk)
    qf[kk] = *(const short8v*)&qb[(size_t)(1 + q0 + lm16) * HD + kk * 32 + lg16 * 8];

  // ---- rel-pos bias tables: bh[r][kh] = q_r . Rh[hq-kh+31], bw likewise ----
  {
    const int r = lm16;
    const int sp = q0 + r;
    const int hq = sp >> 5, wq = sp & 31;
    const unsigned short* qrow = &qb[(size_t)(1 + sp) * HD];
    const float* rp0[16];
#pragma unroll
    for (int i = 0; i < 16; ++i) {
      const int e = lg16 + i * 4;
      rp0[i] = (e < 32) ? &rph[(size_t)(hq - e + 31) * HD]
                        : &rpw[(size_t)(wq - (e - 32) + 31) * HD];
    }
    float accd[16];
#pragma unroll
    for (int i = 0; i < 16; ++i) accd[i] = 0.f;
#pragma unroll
    for (int d8 = 0; d8 < 8; ++d8) {
      short8v qv8 = *(const short8v*)&qrow[d8 * 8];
#pragma unroll
      for (int dd = 0; dd < 8; ++dd) {
        const float qv = b2f((unsigned short)qv8[dd]);
#pragma unroll
        for (int i = 0; i < 16; ++i)
          accd[i] = fmaf(qv, rp0[i][d8 * 8 + dd], accd[i]);
      }
    }
#pragma unroll
    for (int i = 0; i < 16; ++i) {
      const int e = lg16 + i * 4;
      if (e < 32) bh_lds[w * 16 + r][e]      = accd[i];
      else        bw_lds[w * 16 + r][e - 32] = accd[i];
    }
  }
  __syncthreads();

  float mi_r[4];
#pragma unroll
  for (int r4 = 0; r4 < 4; ++r4)
    mi_r[r4] = mask_f[b * N_ + 1 + q0 + lg16 * 4 + r4];

  float m_run[4], l_run[4];
#pragma unroll
  for (int r4 = 0; r4 < 4; ++r4) { m_run[r4] = -1e30f; l_run[r4] = 0.f; }
  f32x4 oacc[4];
#pragma unroll
  for (int dt = 0; dt < 4; ++dt) oacc[dt] = (f32x4){0.f, 0.f, 0.f, 0.f};

  const int w16 = w * 16;
  unsigned short* pl = &p_lds[w][0];
  const short8v z8 = {0, 0, 0, 0, 0, 0, 0, 0};

  for (int kt = 0; kt < 33; ++kt) {
    const int kv0 = kt * 32;
    // ---- QK^T: S[16q][32kv] in two 16-col fragments ----
    f32x4 s[2];
#pragma unroll
    for (int nt = 0; nt < 2; ++nt) {
      const int kvr = kv0 + nt * 16 + lm16;
      f32x4 sa = (f32x4){0.f, 0.f, 0.f, 0.f};
#pragma unroll
      for (int kk = 0; kk < 2; ++kk) {
        short8v kf = z8;
        if (kvr <= 1024)
          kf = *(const short8v*)&kb[(size_t)kvr * HD + kk * 32 + lg16 * 8];
        sa = __builtin_amdgcn_mfma_f32_16x16x32_bf16(qf[kk], kf, sa, 0, 0, 0);
      }
      s[nt] = sa;
    }
    // ---- softmax (online), C layout: col = lm16 (+16*nt), row = lg16*4+reg --
    float lg_[2][4];
#pragma unroll
    for (int nt = 0; nt < 2; ++nt) {
      const int kv = kv0 + nt * 16 + lm16;
      const float mj = (kv <= 1024) ? mask_f[b * N_ + kv] : 0.f;
#pragma unroll
      for (int reg = 0; reg < 4; ++reg) {
        float val = -1e30f;
        if (kv <= 1024) {
          const int r = lg16 * 4 + reg;
          float bias2 = 0.f;
          if (kv >= 1) {
            const int ks = kv - 1;
            bias2 = bh_lds[w16 + r][ks >> 5] + bw_lds[w16 + r][ks & 31];
          }
          val = 0.125f * s[nt][reg] + bias2 - 1e9f * (1.f - mi_r[reg] * mj);
        }
        lg_[nt][reg] = val;
      }
    }
#pragma unroll
    for (int reg = 0; reg < 4; ++reg) {
      float tmax = fmaxf(lg_[0][reg], lg_[1][reg]);
      tmax = fmaxf(tmax, __shfl_xor(tmax, 1));
      tmax = fmaxf(tmax, __shfl_xor(tmax, 2));
      tmax = fmaxf(tmax, __shfl_xor(tmax, 4));
      tmax = fmaxf(tmax, __shfl_xor(tmax, 8));
      const float nm = fmaxf(m_run[reg], tmax);
      const float rf = __expf(m_run[reg] - nm);
      const float p0 = __expf(lg_[0][reg] - nm);
      const float p1 = __expf(lg_[1][reg] - nm);
      float ps = p0 + p1;
      ps += __shfl_xor(ps, 1);
      ps += __shfl_xor(ps, 2);
      ps += __shfl_xor(ps, 4);
      ps += __shfl_xor(ps, 8);
      l_run[reg] = l_run[reg] * rf + ps;
      m_run[reg] = nm;
#pragma unroll
      for (int dt = 0; dt < 4; ++dt) oacc[dt][reg] *= rf;
      pl[(lg16 * 4 + reg) * 40 + lm16]      = f2b(p0);
      pl[(lg16 * 4 + reg) * 40 + 16 + lm16] = f2b(p1);
    }
    // ---- PV: O[16q][64d] += P[16q][32kv] * V[32kv][64d] ----
    const short8v pa = *(const short8v*)&pl[lm16 * 40 + lg16 * 8];
#pragma unroll
    for (int dt = 0; dt < 4; ++dt) {
      const short8v vf =
          *(const short8v*)&vb[(size_t)(dt * 16 + lm16) * NPAD + kv0 + lg16 * 8];
      oacc[dt] = __builtin_amdgcn_mfma_f32_16x16x32_bf16(pa, vf, oacc[dt], 0, 0, 0);
    }
  }

  // ---- epilogue: O row = lg16*4+reg, col d = dt*16+lm16 ----
#pragma unroll
  for (int dt = 0; dt < 4; ++dt)
#pragma unroll
    for (int reg = 0; reg < 4; ++reg) {
      const int nsp = q0 + lg16 * 4 + reg;
      const float val = oacc[dt][reg] / l_run[reg];
      ao[((size_t)(b * NSP + nsp)) * DIM + head * HD + dt * 16 + lm16] = f2b(val);
    }
}

// ---------------- masked avg + max pooling ----------------
__global__ __launch_bounds__(256) void pool_kernel(
    const float* __restrict__ proj_out, const float* __restrict__ mask_f,
    float* __restrict__ out)
{
  const int b = blockIdx.y;
  const int c = blockIdx.x * 256 + threadIdx.x;   // 0..767
  float sum = 0.f, cnt = 0.f, mx = -3.402823466e+38f;
  for (int n = 0; n < NSP; ++n) {
    const float m  = mask_f[b * N_ + 1 + n];
    const float vv = proj_out[((size_t)(b * NSP + n)) * DIM + c];
    sum = fmaf(vv, m, sum);
    cnt += m;
    mx = fmaxf(mx, vv);
  }
  out[b * 1536 + c]       = sum / (cnt + 1e-7f);
  out[b * 1536 + 768 + c] = mx;
}

// ---------------- launch ----------------
extern "C" void kernel_launch(void* const* d_in, const int* in_sizes, int n_in,
                              void* d_out, int out_size, void* d_ws, size_t ws_size,
                              hipStream_t stream) {
  const float* x      = (const float*)d_in[0];
  const unsigned char* mraw = (const unsigned char*)d_in[1];
  const float* qkv_w  = (const float*)d_in[2];
  const float* qkv_b  = (const float*)d_in[3];
  const float* proj_w = (const float*)d_in[4];
  const float* proj_b = (const float*)d_in[5];
  const float* rph    = (const float*)d_in[6];
  const float* rpw    = (const float*)d_in[7];

  char* ws = (char*)d_ws;
  float*          mask_f = (float*)(ws + OFF_MASK);
  unsigned short* xb     = (unsigned short*)(ws + OFF_XB);
  unsigned short* qkvwT  = (unsigned short*)(ws + OFF_QKVWT);
  unsigned short* projwT = (unsigned short*)(ws + OFF_PROJWT);
  unsigned short* qW     = (unsigned short*)(ws + OFF_Q);
  unsigned short* kW     = (unsigned short*)(ws + OFF_K);
  unsigned short* vW     = (unsigned short*)(ws + OFF_V);
  unsigned short* aoW    = (unsigned short*)(ws + OFF_AO);
  float*          po     = (float*)(ws + OFF_PO);

  mask_convert<<<1, 256, 0, stream>>>(mraw, mask_f, B_ * N_);
  cvt_f32_bf16<<<2048, 256, 0, stream>>>(x, xb, 8200 * 768 / 4);
  transpose_cvt<<<dim3(K3 / 32, 768 / 32), dim3(32, 32), 0, stream>>>(
      qkv_w, qkvwT, 768, K3);
  transpose_cvt<<<dim3(768 / 32, 768 / 32), dim3(32, 32), 0, stream>>>(
      proj_w, projwT, 768, 768);
  hipMemsetAsync(vW, 0, V_BYTES, stream);

  gemm_bf16<0><<<dim3(K3 / 128, 65), 256, 0, stream>>>(
      xb, qkvwT, qkv_b, qW, kW, vW, nullptr, 8200);

  attn_mfma<<<dim3(16, NH, B_), 256, 0, stream>>>(
      qW, kW, vW, mask_f, rph, rpw, aoW);

  gemm_bf16<1><<<dim3(768 / 128, 64), 256, 0, stream>>>(
      aoW, projwT, proj_b, nullptr, nullptr, nullptr, po, 8192);

  pool_kernel<<<dim3(3, B_), 256, 0, stream>>>(po, mask_f, (float*)d_out);
}

// Round 3
// 406.967 us; speedup vs baseline: 5.6696x; 1.2017x over previous
//
#include <hip/hip_runtime.h>
#include <hip/hip_bf16.h>

typedef __attribute__((ext_vector_type(8))) short short8v;
typedef __attribute__((ext_vector_type(4))) float f32x4;

constexpr int B_  = 8;
constexpr int NH  = 12;
constexpr int DIM = 768;
constexpr int HD  = 64;
constexpr int N_  = 1025;
constexpr int NSP = 1024;
constexpr int K3  = 2304;
constexpr int NPAD = 1056;   // padded kv length for V^T rows

// ---- workspace byte offsets (all 256-aligned) ----
constexpr size_t OFF_MASK  = 0;                                    // 8448 f32
constexpr size_t OFF_XB    = 65536;                                // x bf16 [8200][768]
constexpr size_t OFF_QKVWT = OFF_XB + (size_t)8200*768*2;          // qkv_w^T bf16 [2304][768]
constexpr size_t OFF_PROJWT= OFF_QKVWT + (size_t)K3*768*2;         // proj_w^T bf16 [768][768]
constexpr size_t OFF_Q     = OFF_PROJWT + (size_t)768*768*2;       // q bf16 [b][h][1025][64]
constexpr size_t OFF_K     = OFF_Q + (size_t)B_*NH*N_*HD*2;
constexpr size_t OFF_V     = OFF_K + (size_t)B_*NH*N_*HD*2;        // v^T bf16 [b][h][64][NPAD]
constexpr size_t V_BYTES   = (size_t)B_*NH*HD*NPAD*2;
constexpr size_t OFF_AO    = OFF_V + V_BYTES;                      // attn_out bf16 [8192][768]
constexpr size_t OFF_PO    = OFF_AO + (size_t)8192*768*2;          // proj_out f32 [8192][768]
// pool partials overlap the (dead-by-then) xb region
constexpr size_t OFF_PS    = OFF_XB;                               // [64][768] f32
constexpr size_t OFF_PM    = OFF_PS + 64*768*4;                    // [64][768] f32
constexpr size_t OFF_PC    = OFF_PM + 64*768*4;                    // [64] f32

__device__ inline float b2f(unsigned short u) {
  union { unsigned int ui; float f; } x; x.ui = ((unsigned int)u) << 16; return x.f;
}
__device__ inline unsigned short f2b(float f) {
  union { float f; unsigned int u; } x; x.f = f;
  unsigned int r = x.u + 0x7FFFu + ((x.u >> 16) & 1u);
  return (unsigned short)(r >> 16);
}
__device__ inline unsigned int cvtpk(float lo, float hi) {
  unsigned int r;
  asm("v_cvt_pk_bf16_f32 %0, %1, %2" : "=v"(r) : "v"(lo), "v"(hi));
  return r;
}

// ---------------- mask dtype detection + canonicalize ----------------
__global__ void mask_convert(const unsigned char* __restrict__ mraw,
                             float* __restrict__ mask_f, int n) {
  __shared__ int flags[2];
  int t = threadIdx.x;
  if (t < 2) flags[t] = 0;
  __syncthreads();
  int f1 = 0, f0 = 0;
  for (int i = t; i < n; i += blockDim.x) {
    unsigned char vv = mraw[i];
    if (vv) { int m = i & 3; if (m == 1) f1 = 1; if (m == 0) f0 = 1; }
  }
  if (f1) atomicOr(&flags[0], 1);
  if (f0) atomicOr(&flags[1], 1);
  __syncthreads();
  bool isBool = flags[0] != 0;
  bool isInt  = !isBool && (flags[1] != 0);
  for (int i = t; i < n; i += blockDim.x) {
    float v;
    if (isBool)     v = mraw[i] ? 1.f : 0.f;
    else if (isInt) v = ((const int*)mraw)[i] ? 1.f : 0.f;
    else            v = ((const float*)mraw)[i];
    mask_f[i] = v;
  }
}

// ---------------- f32 -> bf16 elementwise convert ----------------
__global__ __launch_bounds__(256) void cvt_f32_bf16(
    const float* __restrict__ in, unsigned short* __restrict__ out, int n4) {
  const int stride = gridDim.x * blockDim.x;
  for (int i = blockIdx.x * blockDim.x + threadIdx.x; i < n4; i += stride) {
    float4 v = *(const float4*)&in[i * 4];
    ushort4 u;
    u.x = f2b(v.x); u.y = f2b(v.y); u.z = f2b(v.z); u.w = f2b(v.w);
    *(ushort4*)&out[i * 4] = u;
  }
}

// ---------------- f32 [K][N] -> bf16 transposed [N][K] ----------------
__global__ void transpose_cvt(const float* __restrict__ in,
                              unsigned short* __restrict__ out, int K, int N) {
  __shared__ float tile[32][33];
  const int tx = threadIdx.x, ty = threadIdx.y;
  const int n = blockIdx.x * 32 + tx, k = blockIdx.y * 32 + ty;
  tile[ty][tx] = in[(size_t)k * N + n];
  __syncthreads();
  out[(size_t)(blockIdx.x * 32 + ty) * K + blockIdx.y * 32 + tx] = f2b(tile[tx][ty]);
}

// ---------------- bf16 MFMA GEMM (unchanged from round 2) ----------------
template<int MODE>
__global__ __launch_bounds__(256) void gemm_bf16(
    const unsigned short* __restrict__ A, const unsigned short* __restrict__ BT,
    const float* __restrict__ bias,
    unsigned short* __restrict__ qo, unsigned short* __restrict__ ko,
    unsigned short* __restrict__ vo, float* __restrict__ po, int M)
{
  constexpr int LDK = 768;
  __shared__ unsigned short As[128 * 40];
  __shared__ unsigned short Bs[128 * 40];
  const int t = threadIdx.x;
  const int l = t & 63, w = t >> 6;
  const int lg16 = l >> 4, lm16 = l & 15;
  const int wr = w >> 1, wc = w & 1;
  const int m0 = blockIdx.y * 128, n0 = blockIdx.x * 128;

  f32x4 acc[4][4];
#pragma unroll
  for (int i = 0; i < 4; ++i)
#pragma unroll
    for (int j = 0; j < 4; ++j) acc[i][j] = (f32x4){0.f, 0.f, 0.f, 0.f};

  const int srow = t >> 1, soff = (t & 1) * 16;
  const unsigned short* Aptr = A + (size_t)(m0 + srow) * LDK + soff;
  const unsigned short* Bptr = BT + (size_t)(n0 + srow) * LDK + soff;
  const bool avalid = (MODE == 0) ? (m0 + srow < M) : true;
  const short8v z8 = {0, 0, 0, 0, 0, 0, 0, 0};

  for (int k0 = 0; k0 < LDK; k0 += 32) {
    short8v a0 = z8, a1 = z8;
    if (avalid) {
      a0 = *(const short8v*)(Aptr + k0);
      a1 = *(const short8v*)(Aptr + k0 + 8);
    }
    short8v b0 = *(const short8v*)(Bptr + k0);
    short8v b1 = *(const short8v*)(Bptr + k0 + 8);
    __syncthreads();
    *(short8v*)&As[srow * 40 + soff]     = a0;
    *(short8v*)&As[srow * 40 + soff + 8] = a1;
    *(short8v*)&Bs[srow * 40 + soff]     = b0;
    *(short8v*)&Bs[srow * 40 + soff + 8] = b1;
    __syncthreads();
    short8v af[4], bf[4];
#pragma unroll
    for (int mi = 0; mi < 4; ++mi)
      af[mi] = *(short8v*)&As[(wr * 64 + mi * 16 + lm16) * 40 + lg16 * 8];
#pragma unroll
    for (int ni = 0; ni < 4; ++ni)
      bf[ni] = *(short8v*)&Bs[(wc * 64 + ni * 16 + lm16) * 40 + lg16 * 8];
#pragma unroll
    for (int mi = 0; mi < 4; ++mi)
#pragma unroll
      for (int ni = 0; ni < 4; ++ni)
        acc[mi][ni] = __builtin_amdgcn_mfma_f32_16x16x32_bf16(
            af[mi], bf[ni], acc[mi][ni], 0, 0, 0);
  }

  if (MODE == 1) {
#pragma unroll
    for (int mi = 0; mi < 4; ++mi) {
      const int row0 = m0 + wr * 64 + mi * 16 + lg16 * 4;
#pragma unroll
      for (int ni = 0; ni < 4; ++ni) {
        const int col = n0 + wc * 64 + ni * 16 + lm16;
        const float bv = bias[col];
#pragma unroll
        for (int r = 0; r < 4; ++r)
          po[(size_t)(row0 + r) * 768 + col] = acc[mi][ni][r] + bv;
      }
    }
  } else {
#pragma unroll
    for (int mi = 0; mi < 4; ++mi) {
      const int row0 = m0 + wr * 64 + mi * 16 + lg16 * 4;
#pragma unroll
      for (int ni = 0; ni < 4; ++ni) {
        const int col = n0 + wc * 64 + ni * 16 + lm16;
        const int which = col / 768;
        const int rem = col - which * 768;
        const int head = rem >> 6, d = rem & 63;
        const float bv = bias[col];
#pragma unroll
        for (int r = 0; r < 4; ++r) {
          const int grow = row0 + r;
          if (grow >= M) continue;
          const int b = grow / 1025;
          const int n = grow - b * 1025;
          const unsigned short val = f2b(acc[mi][ni][r] + bv);
          if (which == 0)
            qo[((size_t)(b * NH + head) * N_ + n) * HD + d] = val;
          else if (which == 1)
            ko[((size_t)(b * NH + head) * N_ + n) * HD + d] = val;
          else
            vo[((size_t)(b * NH + head) * HD + d) * NPAD + n] = val;
        }
      }
    }
  }
}

// ---------------- MFMA flash attention v2 (swapped QK^T) ----------------
// 4 waves/block, wave owns 16 q rows. S^T = mfma(K,Q): lane holds q=lm16,
// kv=(lg16*4+reg)+16nt -> softmax reduce = in-reg + 2 shfl. P goes through a
// small per-wave LDS tile into PV A-fragment layout.
__global__ __launch_bounds__(256) void attn_mfma(
    const unsigned short* __restrict__ qp, const unsigned short* __restrict__ kp,
    const unsigned short* __restrict__ vp, const float* __restrict__ mask_f,
    const float* __restrict__ rph, const float* __restrict__ rpw,
    unsigned short* __restrict__ ao)
{
  const int qt = blockIdx.x, head = blockIdx.y, b = blockIdx.z;
  const int t = threadIdx.x, l = t & 63, w = t >> 6;
  const int lg16 = l >> 4, lm16 = l & 15;
  const int w16 = w * 16;

  __shared__ float bh_lds[64][33];       // [q][kh 0..32], col 32 = 0
  __shared__ float bw_lds[64][32];       // [q][kw]
  __shared__ float ct_lds[NPAD];         // column mask term
  __shared__ unsigned int p_lds[4][16 * 20];  // per-wave P, word pitch 20

  const size_t bh_off = (size_t)(b * NH + head) * N_ * HD;
  const unsigned short* qb = qp + bh_off;
  const unsigned short* kb = kp + bh_off;
  const unsigned short* vb = vp + (size_t)(b * NH + head) * HD * NPAD;
  const int q0 = qt * 64 + w16;          // spatial base row for this wave

  // ---- column term fill (block-wide) ----
  for (int i = t; i < NPAD; i += 256)
    ct_lds[i] = (i < N_) ? (-1e9f * (1.f - mask_f[b * N_ + i])) : -1e30f;

  // ---- Q fragments (B operand): col=lm16=q, k(d)=kk*32+lg16*8+j ----
  short8v qf[2];
#pragma unroll
  for (int kk = 0; kk < 2; ++kk)
    qf[kk] = *(const short8v*)&qb[(size_t)(1 + q0 + lm16) * HD + kk * 32 + lg16 * 8];

  // ---- rel-pos bias tables (per wave, rows q0..q0+15) ----
  {
    const int r = lm16, sp = q0 + r;
    const int hq = sp >> 5, wq = sp & 31;
    const unsigned short* qrow = &qb[(size_t)(1 + sp) * HD];
    const float* rp0[16];
#pragma unroll
    for (int i = 0; i < 16; ++i) {
      const int e = lg16 + i * 4;
      rp0[i] = (e < 32) ? &rph[(size_t)(hq - e + 31) * HD]
                        : &rpw[(size_t)(wq - (e - 32) + 31) * HD];
    }
    float accd[16];
#pragma unroll
    for (int i = 0; i < 16; ++i) accd[i] = 0.f;
#pragma unroll
    for (int d4 = 0; d4 < 16; ++d4) {
      ushort4 qu = *(const ushort4*)&qrow[d4 * 4];
      const float a0 = b2f(qu.x), a1 = b2f(qu.y), a2 = b2f(qu.z), a3 = b2f(qu.w);
#pragma unroll
      for (int i = 0; i < 16; ++i) {
        float4 r4 = *(const float4*)(rp0[i] + d4 * 4);
        accd[i] = fmaf(a0, r4.x, fmaf(a1, r4.y, fmaf(a2, r4.z, fmaf(a3, r4.w, accd[i]))));
      }
    }
#pragma unroll
    for (int i = 0; i < 16; ++i) {
      const int e = lg16 + i * 4;
      if (e < 32) bh_lds[w16 + r][e]      = accd[i];
      else        bw_lds[w16 + r][e - 32] = accd[i];
    }
    if (lg16 == 0) bh_lds[w16 + r][32] = 0.f;
  }
  __syncthreads();

  // ---- per-lane preloads ----
  const float mi_s = mask_f[b * N_ + 1 + q0 + lm16];
  const bool mzero = (mi_s == 0.f);
  float bwv[2][4];
#pragma unroll
  for (int nt = 0; nt < 2; ++nt)
#pragma unroll
    for (int reg = 0; reg < 4; ++reg)
      bwv[nt][reg] = bw_lds[w16 + lm16][(lg16 * 4 + reg + 16 * nt + 31) & 31];
  const float bw31v = bw_lds[w16 + lm16][31];

  float m_lm = -1e30f, l_lm = 0.f, bh_prev = 0.f;
  f32x4 oacc[4];
#pragma unroll
  for (int dt = 0; dt < 4; ++dt) oacc[dt] = (f32x4){0.f, 0.f, 0.f, 0.f};

  for (int kt = 0; kt < 33; ++kt) {
    const int kv0 = kt * 32;
    // ---- K fragments (A operand): row=lm16 -> kv, k(d)=kk*32+lg16*8+j ----
    short8v kf[2][2];
#pragma unroll
    for (int nt = 0; nt < 2; ++nt)
#pragma unroll
      for (int kk = 0; kk < 2; ++kk)
        kf[nt][kk] = *(const short8v*)
            &kb[(size_t)(kv0 + nt * 16 + lm16) * HD + kk * 32 + lg16 * 8];
    // ---- S^T: col=lm16=q, row=lg16*4+reg=kv_local ----
    f32x4 s[2];
#pragma unroll
    for (int nt = 0; nt < 2; ++nt) {
      f32x4 sa = (f32x4){0.f, 0.f, 0.f, 0.f};
      sa = __builtin_amdgcn_mfma_f32_16x16x32_bf16(kf[nt][0], qf[0], sa, 0, 0, 0);
      sa = __builtin_amdgcn_mfma_f32_16x16x32_bf16(kf[nt][1], qf[1], sa, 0, 0, 0);
      s[nt] = sa;
    }
    // ---- logits ----
    const float bh_k = bh_lds[w16 + lm16][kt];
    const float edgebias = (kt == 0) ? 0.f : (bh_prev + bw31v);
    bh_prev = bh_k;
    f32x4 ct4[2];
#pragma unroll
    for (int nt = 0; nt < 2; ++nt)
      ct4[nt] = *(const f32x4*)&ct_lds[kv0 + nt * 16 + lg16 * 4];
    float lg_[2][4];
#pragma unroll
    for (int nt = 0; nt < 2; ++nt)
#pragma unroll
      for (int reg = 0; reg < 4; ++reg) {
        float bias2 = bh_k + bwv[nt][reg];
        if (nt == 0 && reg == 0) bias2 = (lg16 == 0) ? edgebias : bias2;
        const float ctv = ct4[nt][reg];
        const float ec = mzero ? fminf(ctv, -1e9f) : ctv;
        lg_[nt][reg] = fmaf(0.125f, s[nt][reg], bias2 + ec);
      }
    // ---- online softmax (q = lm16 domain) ----
    float tm = fmaxf(fmaxf(fmaxf(lg_[0][0], lg_[0][1]), fmaxf(lg_[0][2], lg_[0][3])),
                     fmaxf(fmaxf(lg_[1][0], lg_[1][1]), fmaxf(lg_[1][2], lg_[1][3])));
    tm = fmaxf(tm, __shfl_xor(tm, 16));
    tm = fmaxf(tm, __shfl_xor(tm, 32));
    const float nm = fmaxf(m_lm, tm);
    const float rf_lm = __expf(m_lm - nm);
    m_lm = nm;
    float p[2][4], ps = 0.f;
#pragma unroll
    for (int nt = 0; nt < 2; ++nt)
#pragma unroll
      for (int reg = 0; reg < 4; ++reg) {
        p[nt][reg] = __expf(lg_[nt][reg] - nm);
        ps += p[nt][reg];
      }
    ps += __shfl_xor(ps, 16);
    ps += __shfl_xor(ps, 32);
    l_lm = l_lm * rf_lm + ps;
    // ---- rescale oacc (q = lg16*4+reg domain) ----
    float rfr[4];
#pragma unroll
    for (int reg = 0; reg < 4; ++reg) rfr[reg] = __shfl(rf_lm, lg16 * 4 + reg);
#pragma unroll
    for (int dt = 0; dt < 4; ++dt)
#pragma unroll
      for (int reg = 0; reg < 4; ++reg) oacc[dt][reg] *= rfr[reg];
    // ---- P -> bf16 -> per-wave LDS (row q=lm16, word = kv/2) ----
    unsigned int* pw = &p_lds[w][lm16 * 20 + lg16 * 2];
    pw[0] = cvtpk(p[0][0], p[0][1]);
    pw[1] = cvtpk(p[0][2], p[0][3]);
    pw[8] = cvtpk(p[1][0], p[1][1]);
    pw[9] = cvtpk(p[1][2], p[1][3]);
    // ---- PV: A=P (row=lm16=q, k=lg16*8+j=kv), B=V^T ----
    const short8v pa = *(const short8v*)&p_lds[w][lm16 * 20 + lg16 * 4];
#pragma unroll
    for (int dt = 0; dt < 4; ++dt) {
      const short8v vf =
          *(const short8v*)&vb[(size_t)(dt * 16 + lm16) * NPAD + kv0 + lg16 * 8];
      oacc[dt] = __builtin_amdgcn_mfma_f32_16x16x32_bf16(pa, vf, oacc[dt], 0, 0, 0);
    }
  }

  // ---- epilogue: O row q=lg16*4+reg, col d=dt*16+lm16 ----
  float inv[4];
#pragma unroll
  for (int reg = 0; reg < 4; ++reg)
    inv[reg] = 1.f / __shfl(l_lm, lg16 * 4 + reg);
#pragma unroll
  for (int dt = 0; dt < 4; ++dt)
#pragma unroll
    for (int reg = 0; reg < 4; ++reg) {
      const int nsp = q0 + lg16 * 4 + reg;
      const float val = oacc[dt][reg] * inv[reg];
      ao[((size_t)(b * NSP + nsp)) * DIM + head * HD + dt * 16 + lm16] = f2b(val);
    }
}

// ---------------- two-stage masked avg + max pooling ----------------
__global__ __launch_bounds__(256) void pool_stage1(
    const float* __restrict__ po, const float* __restrict__ mask_f,
    float* __restrict__ psum, float* __restrict__ pmax, float* __restrict__ pcnt)
{
  const int b = blockIdx.y, z = blockIdx.z, cx = blockIdx.x;
  const int c = cx * 256 + threadIdx.x;
  const int n0 = z * 128;
  float sum = 0.f, mx = -3.402823466e+38f;
  for (int n = n0; n < n0 + 128; ++n) {
    const float m = mask_f[b * N_ + 1 + n];
    const float v = po[((size_t)(b * NSP + n)) * DIM + c];
    sum = fmaf(v, m, sum);
    mx = fmaxf(mx, v);
  }
  psum[(z * 8 + b) * 768 + c] = sum;
  pmax[(z * 8 + b) * 768 + c] = mx;
  if (cx == 0 && threadIdx.x < 128)
    atomicAdd(&pcnt[z * 8 + b], mask_f[b * N_ + 1 + n0 + threadIdx.x]);
}

__global__ __launch_bounds__(256) void pool_stage2(
    const float* __restrict__ psum, const float* __restrict__ pmax,
    const float* __restrict__ pcnt, float* __restrict__ out)
{
  const int b = blockIdx.y;
  const int c = blockIdx.x * 256 + threadIdx.x;
  float s = 0.f, mx = -3.402823466e+38f, cnt = 0.f;
#pragma unroll
  for (int z = 0; z < 8; ++z) {
    s  += psum[(z * 8 + b) * 768 + c];
    mx  = fmaxf(mx, pmax[(z * 8 + b) * 768 + c]);
    cnt += pcnt[z * 8 + b];
  }
  out[b * 1536 + c]       = s / (cnt + 1e-7f);
  out[b * 1536 + 768 + c] = mx;
}

// ---------------- launch ----------------
extern "C" void kernel_launch(void* const* d_in, const int* in_sizes, int n_in,
                              void* d_out, int out_size, void* d_ws, size_t ws_size,
                              hipStream_t stream) {
  const float* x      = (const float*)d_in[0];
  const unsigned char* mraw = (const unsigned char*)d_in[1];
  const float* qkv_w  = (const float*)d_in[2];
  const float* qkv_b  = (const float*)d_in[3];
  const float* proj_w = (const float*)d_in[4];
  const float* proj_b = (const float*)d_in[5];
  const float* rph    = (const float*)d_in[6];
  const float* rpw    = (const float*)d_in[7];

  char* ws = (char*)d_ws;
  float*          mask_f = (float*)(ws + OFF_MASK);
  unsigned short* xb     = (unsigned short*)(ws + OFF_XB);
  unsigned short* qkvwT  = (unsigned short*)(ws + OFF_QKVWT);
  unsigned short* projwT = (unsigned short*)(ws + OFF_PROJWT);
  unsigned short* qW     = (unsigned short*)(ws + OFF_Q);
  unsigned short* kW     = (unsigned short*)(ws + OFF_K);
  unsigned short* vW     = (unsigned short*)(ws + OFF_V);
  unsigned short* aoW    = (unsigned short*)(ws + OFF_AO);
  float*          po     = (float*)(ws + OFF_PO);
  float*          psum   = (float*)(ws + OFF_PS);
  float*          pmax   = (float*)(ws + OFF_PM);
  float*          pcnt   = (float*)(ws + OFF_PC);

  mask_convert<<<1, 256, 0, stream>>>(mraw, mask_f, B_ * N_);
  cvt_f32_bf16<<<2048, 256, 0, stream>>>(x, xb, 8200 * 768 / 4);
  transpose_cvt<<<dim3(K3 / 32, 768 / 32), dim3(32, 32), 0, stream>>>(
      qkv_w, qkvwT, 768, K3);
  transpose_cvt<<<dim3(768 / 32, 768 / 32), dim3(32, 32), 0, stream>>>(
      proj_w, projwT, 768, 768);
  hipMemsetAsync(vW, 0, V_BYTES, stream);

  gemm_bf16<0><<<dim3(K3 / 128, 65), 256, 0, stream>>>(
      xb, qkvwT, qkv_b, qW, kW, vW, nullptr, 8200);

  attn_mfma<<<dim3(16, NH, B_), 256, 0, stream>>>(
      qW, kW, vW, mask_f, rph, rpw, aoW);

  gemm_bf16<1><<<dim3(768 / 128, 64), 256, 0, stream>>>(
      aoW, projwT, proj_b, nullptr, nullptr, nullptr, po, 8192);

  hipMemsetAsync(pcnt, 0, 64 * 4, stream);
  pool_stage1<<<dim3(3, B_, 8), 256, 0, stream>>>(po, mask_f, psum, pmax, pcnt);
  pool_stage2<<<dim3(3, B_), 256, 0, stream>>>(psum, pmax, pcnt, (float*)d_out);
}

// Round 4
// 368.721 us; speedup vs baseline: 6.2577x; 1.1037x over previous
//
#include <hip/hip_runtime.h>
#include <hip/hip_bf16.h>

typedef __attribute__((ext_vector_type(8))) short short8v;
typedef __attribute__((ext_vector_type(4))) float f32x4;

constexpr int B_  = 8;
constexpr int NH  = 12;
constexpr int DIM = 768;
constexpr int HD  = 64;
constexpr int N_  = 1025;
constexpr int NSP = 1024;
constexpr int K3  = 2304;
constexpr int NPAD  = 1056;  // padded kv length for V^T cols
constexpr int KROWS = 1056;  // padded K rows (zeros past 1024)

// ---- workspace byte offsets ----
constexpr size_t OFF_MASK  = 0;
constexpr size_t OFF_XB    = 65536;
constexpr size_t OFF_QKVWT = OFF_XB + (size_t)8200*768*2;
constexpr size_t OFF_PROJWT= OFF_QKVWT + (size_t)K3*768*2;
constexpr size_t OFF_Q     = OFF_PROJWT + (size_t)768*768*2;
constexpr size_t OFF_K     = OFF_Q + (size_t)B_*NH*N_*HD*2;
constexpr size_t K_BYTES   = (size_t)B_*NH*KROWS*HD*2;
constexpr size_t OFF_V     = OFF_K + K_BYTES;
constexpr size_t V_BYTES   = (size_t)B_*NH*HD*NPAD*2;
constexpr size_t OFF_AO    = OFF_V + V_BYTES;
constexpr size_t OFF_PO    = OFF_AO + (size_t)8192*768*2;
// pool partials overlap the (dead-by-then) xb region
constexpr size_t OFF_PS    = OFF_XB;
constexpr size_t OFF_PM    = OFF_PS + 64*768*4;
constexpr size_t OFF_PC    = OFF_PM + 64*768*4;

__device__ inline float b2f(unsigned short u) {
  union { unsigned int ui; float f; } x; x.ui = ((unsigned int)u) << 16; return x.f;
}
__device__ inline unsigned short f2b(float f) {
  union { float f; unsigned int u; } x; x.f = f;
  unsigned int r = x.u + 0x7FFFu + ((x.u >> 16) & 1u);
  return (unsigned short)(r >> 16);
}
__device__ inline unsigned int cvtpk(float lo, float hi) {
  unsigned int r;
  asm("v_cvt_pk_bf16_f32 %0, %1, %2" : "=v"(r) : "v"(lo), "v"(hi));
  return r;
}
__device__ inline void gload16(const void* g, void* l) {
  __builtin_amdgcn_global_load_lds(
      (const __attribute__((address_space(1))) void*)g,
      (__attribute__((address_space(3))) void*)l, 16, 0, 0);
}

// ---------------- mask dtype detection + canonicalize ----------------
__global__ void mask_convert(const unsigned char* __restrict__ mraw,
                             float* __restrict__ mask_f, int n) {
  __shared__ int flags[2];
  int t = threadIdx.x;
  if (t < 2) flags[t] = 0;
  __syncthreads();
  int f1 = 0, f0 = 0;
  for (int i = t; i < n; i += blockDim.x) {
    unsigned char vv = mraw[i];
    if (vv) { int m = i & 3; if (m == 1) f1 = 1; if (m == 0) f0 = 1; }
  }
  if (f1) atomicOr(&flags[0], 1);
  if (f0) atomicOr(&flags[1], 1);
  __syncthreads();
  bool isBool = flags[0] != 0;
  bool isInt  = !isBool && (flags[1] != 0);
  for (int i = t; i < n; i += blockDim.x) {
    float v;
    if (isBool)     v = mraw[i] ? 1.f : 0.f;
    else if (isInt) v = ((const int*)mraw)[i] ? 1.f : 0.f;
    else            v = ((const float*)mraw)[i];
    mask_f[i] = v;
  }
}

// ---------------- zero the K/V pad regions ----------------
__global__ __launch_bounds__(256) void pad_zero(unsigned short* __restrict__ kW,
                                                unsigned short* __restrict__ vW) {
  const int bh = blockIdx.x, t = threadIdx.x;
  unsigned short* kbase = kW + (size_t)bh * KROWS * HD + 1025 * HD;
  for (int i = t; i < 31 * 64; i += 256) kbase[i] = 0;
  unsigned short* vbase = vW + (size_t)bh * HD * NPAD;
  for (int i = t; i < 64 * 31; i += 256) {
    const int d = i / 31, c = i - d * 31;
    vbase[(size_t)d * NPAD + 1025 + c] = 0;
  }
}

// ---------------- f32 -> bf16 elementwise convert ----------------
__global__ __launch_bounds__(256) void cvt_f32_bf16(
    const float* __restrict__ in, unsigned short* __restrict__ out, int n4) {
  const int stride = gridDim.x * blockDim.x;
  for (int i = blockIdx.x * blockDim.x + threadIdx.x; i < n4; i += stride) {
    float4 v = *(const float4*)&in[i * 4];
    ushort4 u;
    u.x = f2b(v.x); u.y = f2b(v.y); u.z = f2b(v.z); u.w = f2b(v.w);
    *(ushort4*)&out[i * 4] = u;
  }
}

// ---------------- f32 [K][N] -> bf16 transposed [N][K] ----------------
__global__ void transpose_cvt(const float* __restrict__ in,
                              unsigned short* __restrict__ out, int K, int N) {
  __shared__ float tile[32][33];
  const int tx = threadIdx.x, ty = threadIdx.y;
  const int n = blockIdx.x * 32 + tx, k = blockIdx.y * 32 + ty;
  tile[ty][tx] = in[(size_t)k * N + n];
  __syncthreads();
  out[(size_t)(blockIdx.x * 32 + ty) * K + blockIdx.y * 32 + tx] = f2b(tile[tx][ty]);
}

// ---------------- bf16 MFMA GEMM ----------------
template<int MODE>
__global__ __launch_bounds__(256) void gemm_bf16(
    const unsigned short* __restrict__ A, const unsigned short* __restrict__ BT,
    const float* __restrict__ bias,
    unsigned short* __restrict__ qo, unsigned short* __restrict__ ko,
    unsigned short* __restrict__ vo, float* __restrict__ po, int M)
{
  constexpr int LDK = 768;
  __shared__ unsigned short As[128 * 40];
  __shared__ unsigned short Bs[128 * 40];
  const int t = threadIdx.x;
  const int l = t & 63, w = t >> 6;
  const int lg16 = l >> 4, lm16 = l & 15;
  const int wr = w >> 1, wc = w & 1;
  const int m0 = blockIdx.y * 128, n0 = blockIdx.x * 128;

  f32x4 acc[4][4];
#pragma unroll
  for (int i = 0; i < 4; ++i)
#pragma unroll
    for (int j = 0; j < 4; ++j) acc[i][j] = (f32x4){0.f, 0.f, 0.f, 0.f};

  const int srow = t >> 1, soff = (t & 1) * 16;
  const unsigned short* Aptr = A + (size_t)(m0 + srow) * LDK + soff;
  const unsigned short* Bptr = BT + (size_t)(n0 + srow) * LDK + soff;
  const bool avalid = (MODE == 0) ? (m0 + srow < M) : true;
  const short8v z8 = {0, 0, 0, 0, 0, 0, 0, 0};

  for (int k0 = 0; k0 < LDK; k0 += 32) {
    short8v a0 = z8, a1 = z8;
    if (avalid) {
      a0 = *(const short8v*)(Aptr + k0);
      a1 = *(const short8v*)(Aptr + k0 + 8);
    }
    short8v b0 = *(const short8v*)(Bptr + k0);
    short8v b1 = *(const short8v*)(Bptr + k0 + 8);
    __syncthreads();
    *(short8v*)&As[srow * 40 + soff]     = a0;
    *(short8v*)&As[srow * 40 + soff + 8] = a1;
    *(short8v*)&Bs[srow * 40 + soff]     = b0;
    *(short8v*)&Bs[srow * 40 + soff + 8] = b1;
    __syncthreads();
    short8v af[4], bf[4];
#pragma unroll
    for (int mi = 0; mi < 4; ++mi)
      af[mi] = *(short8v*)&As[(wr * 64 + mi * 16 + lm16) * 40 + lg16 * 8];
#pragma unroll
    for (int ni = 0; ni < 4; ++ni)
      bf[ni] = *(short8v*)&Bs[(wc * 64 + ni * 16 + lm16) * 40 + lg16 * 8];
#pragma unroll
    for (int mi = 0; mi < 4; ++mi)
#pragma unroll
      for (int ni = 0; ni < 4; ++ni)
        acc[mi][ni] = __builtin_amdgcn_mfma_f32_16x16x32_bf16(
            af[mi], bf[ni], acc[mi][ni], 0, 0, 0);
  }

  if (MODE == 1) {
#pragma unroll
    for (int mi = 0; mi < 4; ++mi) {
      const int row0 = m0 + wr * 64 + mi * 16 + lg16 * 4;
#pragma unroll
      for (int ni = 0; ni < 4; ++ni) {
        const int col = n0 + wc * 64 + ni * 16 + lm16;
        const float bv = bias[col];
#pragma unroll
        for (int r = 0; r < 4; ++r)
          po[(size_t)(row0 + r) * 768 + col] = acc[mi][ni][r] + bv;
      }
    }
  } else {
#pragma unroll
    for (int mi = 0; mi < 4; ++mi) {
      const int row0 = m0 + wr * 64 + mi * 16 + lg16 * 4;
#pragma unroll
      for (int ni = 0; ni < 4; ++ni) {
        const int col = n0 + wc * 64 + ni * 16 + lm16;
        const int which = col / 768;
        const int rem = col - which * 768;
        const int head = rem >> 6, d = rem & 63;
        const float bv = bias[col];
#pragma unroll
        for (int r = 0; r < 4; ++r) {
          const int grow = row0 + r;
          if (grow >= M) continue;
          const int b = grow / 1025;
          const int n = grow - b * 1025;
          const unsigned short val = f2b(acc[mi][ni][r] + bv);
          if (which == 0)
            qo[((size_t)(b * NH + head) * N_ + n) * HD + d] = val;
          else if (which == 1)
            ko[((size_t)(b * NH + head) * KROWS + n) * HD + d] = val;
          else
            vo[((size_t)(b * NH + head) * HD + d) * NPAD + n] = val;
        }
      }
    }
  }
}

// ---------------- MFMA flash attention v3 ----------------
// 4 waves/block, wave owns 16 q rows. LDS-staged K/V tiles (double-buffered,
// global_load_lds w/ pre-swizzled source), counted vmcnt, defer-max softmax.
__global__ __launch_bounds__(256) void attn_mfma(
    const unsigned short* __restrict__ qp, const unsigned short* __restrict__ kp,
    const unsigned short* __restrict__ vp, const float* __restrict__ mask_f,
    const float* __restrict__ rph, const float* __restrict__ rpw,
    unsigned short* __restrict__ ao)
{
  // bijective XCD swizzle: XCD x owns 12 (b,head) pairs x 16 q-tiles
  const int bid = blockIdx.x;
  const int work = (bid & 7) * 192 + (bid >> 3);
  const int qt = work & 15;
  const int bh = work >> 4;               // 0..95 = b*NH+head
  const int b = bh / NH, head = bh - b * NH;

  const int t = threadIdx.x, l = t & 63, w = t >> 6;
  const int lg16 = l >> 4, lm16 = l & 15;
  const int w16 = w * 16;
  constexpr float L2E = 1.44269504f;
  constexpr float SCL = 0.125f * L2E;
  constexpr float MCOL = -1.44269504e9f;  // -1e9 * log2e
  constexpr float THR_L = 11.5f;          // defer-max threshold (8 nats)

  __shared__ float bh_lds[64][33];        // [q][kh 0..32] * log2e, col32=0
  __shared__ float bw_lds[64][32];        // [q][kw] * log2e
  __shared__ float ct_lds[NPAD];          // column mask term * log2e
  __shared__ unsigned int p_lds[4][16 * 20];
  __shared__ unsigned short kbuf[2][32 * 64];  // K tile, chunk^=(row&7)
  __shared__ unsigned short vbuf[2][64 * 32];  // V^T tile, chunk^=((row>>1)&3)

  const unsigned short* qb = qp + (size_t)bh * N_ * HD;
  const unsigned short* kb = kp + (size_t)bh * KROWS * HD;
  const unsigned short* vb = vp + (size_t)bh * HD * NPAD;
  const int q0 = qt * 64 + w16;

  // ---- column term fill ----
  for (int i = t; i < NPAD; i += 256)
    ct_lds[i] = (i < N_) ? (MCOL * (1.f - mask_f[b * N_ + i])) : -2e30f;

  // ---- Q fragments (B operand) ----
  short8v qf[2];
#pragma unroll
  for (int kk = 0; kk < 2; ++kk)
    qf[kk] = *(const short8v*)&qb[(size_t)(1 + q0 + lm16) * HD + kk * 32 + lg16 * 8];

  // ---- rel-pos bias tables (x log2e) ----
  {
    const int r = lm16, sp = q0 + r;
    const int hq = sp >> 5, wq = sp & 31;
    const unsigned short* qrow = &qb[(size_t)(1 + sp) * HD];
    const float* rp0[16];
#pragma unroll
    for (int i = 0; i < 16; ++i) {
      const int e = lg16 + i * 4;
      rp0[i] = (e < 32) ? &rph[(size_t)(hq - e + 31) * HD]
                        : &rpw[(size_t)(wq - (e - 32) + 31) * HD];
    }
    float accd[16];
#pragma unroll
    for (int i = 0; i < 16; ++i) accd[i] = 0.f;
#pragma unroll
    for (int d4 = 0; d4 < 16; ++d4) {
      ushort4 qu = *(const ushort4*)&qrow[d4 * 4];
      const float a0 = b2f(qu.x), a1 = b2f(qu.y), a2 = b2f(qu.z), a3 = b2f(qu.w);
#pragma unroll
      for (int i = 0; i < 16; ++i) {
        float4 r4 = *(const float4*)(rp0[i] + d4 * 4);
        accd[i] = fmaf(a0, r4.x, fmaf(a1, r4.y, fmaf(a2, r4.z, fmaf(a3, r4.w, accd[i]))));
      }
    }
#pragma unroll
    for (int i = 0; i < 16; ++i) {
      const int e = lg16 + i * 4;
      if (e < 32) bh_lds[w16 + r][e]      = accd[i] * L2E;
      else        bw_lds[w16 + r][e - 32] = accd[i] * L2E;
    }
    if (lg16 == 0) bh_lds[w16 + r][32] = 0.f;
  }
  __syncthreads();

  // ---- per-lane preloads ----
  const float mi_s = mask_f[b * N_ + 1 + q0 + lm16];
  const bool mzero = (mi_s == 0.f);
  float bwv[2][4];
#pragma unroll
  for (int nt = 0; nt < 2; ++nt)
#pragma unroll
    for (int reg = 0; reg < 4; ++reg)
      bwv[nt][reg] = bw_lds[w16 + lm16][(lg16 * 4 + reg + 16 * nt + 31) & 31];
  const float bw31v = bw_lds[w16 + lm16][31];

  // ---- staging source/dest (pre-swizzled global source, linear LDS dest) --
  const unsigned short* ksrc =
      kb + ((t >> 3) * 64 + (((t & 7) ^ ((t >> 3) & 7)) * 8));
  const unsigned short* vsrc =
      vb + ((size_t)(t >> 2) * NPAD + (((t & 3) ^ ((t >> 3) & 3)) * 8));
  char* kdst = (char*)&kbuf[0][0] + w * 1024;
  char* vdst = (char*)&vbuf[0][0] + w * 1024;
#define STAGE(bi, kt_)                                                   \
  do {                                                                   \
    gload16(ksrc + (size_t)(kt_) * 2048, kdst + (bi) * 4096);            \
    gload16(vsrc + (size_t)(kt_) * 32,   vdst + (bi) * 4096);            \
  } while (0)

  // ---- fragment LDS offsets (swizzled) ----
  int koff[2][2], voff[4];
#pragma unroll
  for (int nt = 0; nt < 2; ++nt)
#pragma unroll
    for (int kk = 0; kk < 2; ++kk)
      koff[nt][kk] = (nt * 16 + lm16) * 64 + (((kk * 4 + lg16) ^ (lm16 & 7)) * 8);
#pragma unroll
  for (int dt = 0; dt < 4; ++dt)
    voff[dt] = (dt * 16 + lm16) * 32 + ((lg16 ^ ((lm16 >> 1) & 3)) * 8);

  float m_lm = -1e30f, l_lm = 0.f, bh_prev = 0.f;
  f32x4 oacc[4];
#pragma unroll
  for (int dt = 0; dt < 4; ++dt) oacc[dt] = (f32x4){0.f, 0.f, 0.f, 0.f};
  unsigned int* pw = &p_lds[w][lm16 * 20 + lg16 * 2];
  const unsigned int* pr = &p_lds[w][lm16 * 20 + lg16 * 4];

  STAGE(0, 0);

  for (int kt = 0; kt < 33; ++kt) {
    const int cur = kt & 1;
    if (kt < 32) {
      STAGE(cur ^ 1, kt + 1);
      asm volatile("s_waitcnt vmcnt(2)" ::: "memory");
    } else {
      asm volatile("s_waitcnt vmcnt(0)" ::: "memory");
    }
    asm volatile("s_barrier" ::: "memory");

    const unsigned short* Kb = &kbuf[cur][0];
    const unsigned short* Vb = &vbuf[cur][0];

    // ---- S^T = mfma(K, Q): lane holds q=lm16, kv=(lg16*4+reg)+16nt ----
    f32x4 s[2];
#pragma unroll
    for (int nt = 0; nt < 2; ++nt) {
      f32x4 sa = (f32x4){0.f, 0.f, 0.f, 0.f};
      sa = __builtin_amdgcn_mfma_f32_16x16x32_bf16(
          *(const short8v*)&Kb[koff[nt][0]], qf[0], sa, 0, 0, 0);
      sa = __builtin_amdgcn_mfma_f32_16x16x32_bf16(
          *(const short8v*)&Kb[koff[nt][1]], qf[1], sa, 0, 0, 0);
      s[nt] = sa;
    }
    // ---- logits (log2 domain) ----
    const float bh_k = bh_lds[w16 + lm16][kt];
    const float edgebias = (kt == 0) ? 0.f : (bh_prev + bw31v);
    bh_prev = bh_k;
    f32x4 ct4[2];
#pragma unroll
    for (int nt = 0; nt < 2; ++nt)
      ct4[nt] = *(const f32x4*)&ct_lds[kt * 32 + nt * 16 + lg16 * 4];
    float lg_[2][4];
#pragma unroll
    for (int nt = 0; nt < 2; ++nt)
#pragma unroll
      for (int reg = 0; reg < 4; ++reg) {
        float bias2 = bh_k + bwv[nt][reg];
        if (nt == 0 && reg == 0) bias2 = (lg16 == 0) ? edgebias : bias2;
        const float ctv = ct4[nt][reg];
        const float ec = mzero ? fminf(ctv, MCOL) : ctv;
        lg_[nt][reg] = fmaf(SCL, s[nt][reg], bias2 + ec);
      }
    // ---- online softmax with defer-max ----
    float tm = fmaxf(fmaxf(fmaxf(lg_[0][0], lg_[0][1]), fmaxf(lg_[0][2], lg_[0][3])),
                     fmaxf(fmaxf(lg_[1][0], lg_[1][1]), fmaxf(lg_[1][2], lg_[1][3])));
    tm = fmaxf(tm, __shfl_xor(tm, 16));
    tm = fmaxf(tm, __shfl_xor(tm, 32));
    if (__any(tm > m_lm + THR_L)) {
      const float nm = fmaxf(m_lm, tm);
      const float rf = exp2f(m_lm - nm);
      m_lm = nm;
      l_lm *= rf;
      float rfr[4];
#pragma unroll
      for (int reg = 0; reg < 4; ++reg) rfr[reg] = __shfl(rf, lg16 * 4 + reg);
#pragma unroll
      for (int dt = 0; dt < 4; ++dt)
#pragma unroll
        for (int reg = 0; reg < 4; ++reg) oacc[dt][reg] *= rfr[reg];
    }
    float p[2][4], ps = 0.f;
#pragma unroll
    for (int nt = 0; nt < 2; ++nt)
#pragma unroll
      for (int reg = 0; reg < 4; ++reg) {
        p[nt][reg] = exp2f(lg_[nt][reg] - m_lm);
        ps += p[nt][reg];
      }
    ps += __shfl_xor(ps, 16);
    ps += __shfl_xor(ps, 32);
    l_lm += ps;
    // ---- P -> bf16 -> per-wave LDS -> PV A-fragment ----
    pw[0] = cvtpk(p[0][0], p[0][1]);
    pw[1] = cvtpk(p[0][2], p[0][3]);
    pw[8] = cvtpk(p[1][0], p[1][1]);
    pw[9] = cvtpk(p[1][2], p[1][3]);
    const short8v pa = *(const short8v*)pr;
#pragma unroll
    for (int dt = 0; dt < 4; ++dt)
      oacc[dt] = __builtin_amdgcn_mfma_f32_16x16x32_bf16(
          pa, *(const short8v*)&Vb[voff[dt]], oacc[dt], 0, 0, 0);
    asm volatile("s_barrier" ::: "memory");
  }
#undef STAGE

  // ---- epilogue ----
  float inv[4];
#pragma unroll
  for (int reg = 0; reg < 4; ++reg)
    inv[reg] = 1.f / __shfl(l_lm, lg16 * 4 + reg);
#pragma unroll
  for (int dt = 0; dt < 4; ++dt)
#pragma unroll
    for (int reg = 0; reg < 4; ++reg) {
      const int nsp = q0 + lg16 * 4 + reg;
      const float val = oacc[dt][reg] * inv[reg];
      ao[((size_t)(b * NSP + nsp)) * DIM + head * HD + dt * 16 + lm16] = f2b(val);
    }
}

// ---------------- two-stage masked avg + max pooling ----------------
__global__ __launch_bounds__(256) void pool_stage1(
    const float* __restrict__ po, const float* __restrict__ mask_f,
    float* __restrict__ psum, float* __restrict__ pmax, float* __restrict__ pcnt)
{
  const int b = blockIdx.y, z = blockIdx.z, cx = blockIdx.x;
  const int c = cx * 256 + threadIdx.x;
  const int n0 = z * 128;
  float sum = 0.f, mx = -3.402823466e+38f;
  for (int n = n0; n < n0 + 128; ++n) {
    const float m = mask_f[b * N_ + 1 + n];
    const float v = po[((size_t)(b * NSP + n)) * DIM + c];
    sum = fmaf(v, m, sum);
    mx = fmaxf(mx, v);
  }
  psum[(z * 8 + b) * 768 + c] = sum;
  pmax[(z * 8 + b) * 768 + c] = mx;
  if (cx == 0 && threadIdx.x < 128)
    atomicAdd(&pcnt[z * 8 + b], mask_f[b * N_ + 1 + n0 + threadIdx.x]);
}

__global__ __launch_bounds__(256) void pool_stage2(
    const float* __restrict__ psum, const float* __restrict__ pmax,
    const float* __restrict__ pcnt, float* __restrict__ out)
{
  const int b = blockIdx.y;
  const int c = blockIdx.x * 256 + threadIdx.x;
  float s = 0.f, mx = -3.402823466e+38f, cnt = 0.f;
#pragma unroll
  for (int z = 0; z < 8; ++z) {
    s  += psum[(z * 8 + b) * 768 + c];
    mx  = fmaxf(mx, pmax[(z * 8 + b) * 768 + c]);
    cnt += pcnt[z * 8 + b];
  }
  out[b * 1536 + c]       = s / (cnt + 1e-7f);
  out[b * 1536 + 768 + c] = mx;
}

// ---------------- launch ----------------
extern "C" void kernel_launch(void* const* d_in, const int* in_sizes, int n_in,
                              void* d_out, int out_size, void* d_ws, size_t ws_size,
                              hipStream_t stream) {
  const float* x      = (const float*)d_in[0];
  const unsigned char* mraw = (const unsigned char*)d_in[1];
  const float* qkv_w  = (const float*)d_in[2];
  const float* qkv_b  = (const float*)d_in[3];
  const float* proj_w = (const float*)d_in[4];
  const float* proj_b = (const float*)d_in[5];
  const float* rph    = (const float*)d_in[6];
  const float* rpw    = (const float*)d_in[7];

  char* ws = (char*)d_ws;
  float*          mask_f = (float*)(ws + OFF_MASK);
  unsigned short* xb     = (unsigned short*)(ws + OFF_XB);
  unsigned short* qkvwT  = (unsigned short*)(ws + OFF_QKVWT);
  unsigned short* projwT = (unsigned short*)(ws + OFF_PROJWT);
  unsigned short* qW     = (unsigned short*)(ws + OFF_Q);
  unsigned short* kW     = (unsigned short*)(ws + OFF_K);
  unsigned short* vW     = (unsigned short*)(ws + OFF_V);
  unsigned short* aoW    = (unsigned short*)(ws + OFF_AO);
  float*          po     = (float*)(ws + OFF_PO);
  float*          psum   = (float*)(ws + OFF_PS);
  float*          pmax   = (float*)(ws + OFF_PM);
  float*          pcnt   = (float*)(ws + OFF_PC);

  mask_convert<<<1, 256, 0, stream>>>(mraw, mask_f, B_ * N_);
  cvt_f32_bf16<<<2048, 256, 0, stream>>>(x, xb, 8200 * 768 / 4);
  transpose_cvt<<<dim3(K3 / 32, 768 / 32), dim3(32, 32), 0, stream>>>(
      qkv_w, qkvwT, 768, K3);
  transpose_cvt<<<dim3(768 / 32, 768 / 32), dim3(32, 32), 0, stream>>>(
      proj_w, projwT, 768, 768);
  pad_zero<<<96, 256, 0, stream>>>(kW, vW);

  gemm_bf16<0><<<dim3(K3 / 128, 65), 256, 0, stream>>>(
      xb, qkvwT, qkv_b, qW, kW, vW, nullptr, 8200);

  attn_mfma<<<1536, 256, 0, stream>>>(
      qW, kW, vW, mask_f, rph, rpw, aoW);

  gemm_bf16<1><<<dim3(768 / 128, 64), 256, 0, stream>>>(
      aoW, projwT, proj_b, nullptr, nullptr, nullptr, po, 8192);

  hipMemsetAsync(pcnt, 0, 64 * 4, stream);
  pool_stage1<<<dim3(3, B_, 8), 256, 0, stream>>>(po, mask_f, psum, pmax, pcnt);
  pool_stage2<<<dim3(3, B_), 256, 0, stream>>>(psum, pmax, pcnt, (float*)d_out);
}

// Round 5
// 307.764 us; speedup vs baseline: 7.4972x; 1.1981x over previous
//
#include <hip/hip_runtime.h>
#include <hip/hip_bf16.h>

typedef __attribute__((ext_vector_type(8))) short short8v;
typedef __attribute__((ext_vector_type(4))) float f32x4;

constexpr int B_  = 8;
constexpr int NH  = 12;
constexpr int DIM = 768;
constexpr int HD  = 64;
constexpr int N_  = 1025;
constexpr int NSP = 1024;
constexpr int K3  = 2304;
constexpr int NPAD  = 1056;  // padded kv length for V^T cols
constexpr int KROWS = 1056;  // padded K rows (zeros past 1024)

// ---- workspace byte offsets ----
constexpr size_t OFF_MASK  = 0;
constexpr size_t OFF_XB    = 65536;
constexpr size_t OFF_QKVWT = OFF_XB + (size_t)8200*768*2;
constexpr size_t OFF_PROJWT= OFF_QKVWT + (size_t)K3*768*2;
constexpr size_t OFF_Q     = OFF_PROJWT + (size_t)768*768*2;
constexpr size_t OFF_K     = OFF_Q + (size_t)B_*NH*N_*HD*2;
constexpr size_t K_BYTES   = (size_t)B_*NH*KROWS*HD*2;
constexpr size_t OFF_V     = OFF_K + K_BYTES;
constexpr size_t V_BYTES   = (size_t)B_*NH*HD*NPAD*2;
constexpr size_t OFF_AO    = OFF_V + V_BYTES;
constexpr size_t OFF_PO    = OFF_AO + (size_t)8192*768*2;
// pool partials overlap the (dead-by-then) xb region
constexpr size_t OFF_PS    = OFF_XB;
constexpr size_t OFF_PM    = OFF_PS + 64*768*4;
constexpr size_t OFF_PC    = OFF_PM + 64*768*4;

__device__ inline float b2f(unsigned short u) {
  union { unsigned int ui; float f; } x; x.ui = ((unsigned int)u) << 16; return x.f;
}
__device__ inline unsigned short f2b(float f) {
  union { float f; unsigned int u; } x; x.f = f;
  unsigned int r = x.u + 0x7FFFu + ((x.u >> 16) & 1u);
  return (unsigned short)(r >> 16);
}
__device__ inline unsigned int cvtpk(float lo, float hi) {
  unsigned int r;
  asm("v_cvt_pk_bf16_f32 %0, %1, %2" : "=v"(r) : "v"(lo), "v"(hi));
  return r;
}
__device__ inline short8v pack8(float4 lo, float4 hi) {
  union { unsigned int u[4]; short8v s; } r;
  r.u[0] = cvtpk(lo.x, lo.y); r.u[1] = cvtpk(lo.z, lo.w);
  r.u[2] = cvtpk(hi.x, hi.y); r.u[3] = cvtpk(hi.z, hi.w);
  return r.s;
}

// ---------------- mask dtype detection + canonicalize ----------------
__global__ void mask_convert(const unsigned char* __restrict__ mraw,
                             float* __restrict__ mask_f, int n) {
  __shared__ int flags[2];
  int t = threadIdx.x;
  if (t < 2) flags[t] = 0;
  __syncthreads();
  int f1 = 0, f0 = 0;
  for (int i = t; i < n; i += blockDim.x) {
    unsigned char vv = mraw[i];
    if (vv) { int m = i & 3; if (m == 1) f1 = 1; if (m == 0) f0 = 1; }
  }
  if (f1) atomicOr(&flags[0], 1);
  if (f0) atomicOr(&flags[1], 1);
  __syncthreads();
  bool isBool = flags[0] != 0;
  bool isInt  = !isBool && (flags[1] != 0);
  for (int i = t; i < n; i += blockDim.x) {
    float v;
    if (isBool)     v = mraw[i] ? 1.f : 0.f;
    else if (isInt) v = ((const int*)mraw)[i] ? 1.f : 0.f;
    else            v = ((const float*)mraw)[i];
    mask_f[i] = v;
  }
}

// ---------------- zero the K/V pad regions ----------------
__global__ __launch_bounds__(256) void pad_zero(unsigned short* __restrict__ kW,
                                                unsigned short* __restrict__ vW) {
  const int bh = blockIdx.x, t = threadIdx.x;
  unsigned short* kbase = kW + (size_t)bh * KROWS * HD + 1025 * HD;
  for (int i = t; i < 31 * 64; i += 256) kbase[i] = 0;
  unsigned short* vbase = vW + (size_t)bh * HD * NPAD;
  for (int i = t; i < 64 * 31; i += 256) {
    const int d = i / 31, c = i - d * 31;
    vbase[(size_t)d * NPAD + 1025 + c] = 0;
  }
}

// ---------------- f32 -> bf16 elementwise convert ----------------
__global__ __launch_bounds__(256) void cvt_f32_bf16(
    const float* __restrict__ in, unsigned short* __restrict__ out, int n4) {
  const int stride = gridDim.x * blockDim.x;
  for (int i = blockIdx.x * blockDim.x + threadIdx.x; i < n4; i += stride) {
    float4 v = *(const float4*)&in[i * 4];
    ushort4 u;
    u.x = f2b(v.x); u.y = f2b(v.y); u.z = f2b(v.z); u.w = f2b(v.w);
    *(ushort4*)&out[i * 4] = u;
  }
}

// ---------------- f32 [K][N] -> bf16 transposed [N][K] ----------------
__global__ void transpose_cvt(const float* __restrict__ in,
                              unsigned short* __restrict__ out, int K, int N) {
  __shared__ float tile[32][33];
  const int tx = threadIdx.x, ty = threadIdx.y;
  const int n = blockIdx.x * 32 + tx, k = blockIdx.y * 32 + ty;
  tile[ty][tx] = in[(size_t)k * N + n];
  __syncthreads();
  out[(size_t)(blockIdx.x * 32 + ty) * K + blockIdx.y * 32 + tx] = f2b(tile[tx][ty]);
}

// ---------------- bf16 MFMA GEMM ----------------
template<int MODE>
__global__ __launch_bounds__(256) void gemm_bf16(
    const unsigned short* __restrict__ A, const unsigned short* __restrict__ BT,
    const float* __restrict__ bias,
    unsigned short* __restrict__ qo, unsigned short* __restrict__ ko,
    unsigned short* __restrict__ vo, float* __restrict__ po, int M)
{
  constexpr int LDK = 768;
  __shared__ unsigned short As[128 * 40];
  __shared__ unsigned short Bs[128 * 40];
  const int t = threadIdx.x;
  const int l = t & 63, w = t >> 6;
  const int lg16 = l >> 4, lm16 = l & 15;
  const int wr = w >> 1, wc = w & 1;
  const int m0 = blockIdx.y * 128, n0 = blockIdx.x * 128;

  f32x4 acc[4][4];
#pragma unroll
  for (int i = 0; i < 4; ++i)
#pragma unroll
    for (int j = 0; j < 4; ++j) acc[i][j] = (f32x4){0.f, 0.f, 0.f, 0.f};

  const int srow = t >> 1, soff = (t & 1) * 16;
  const unsigned short* Aptr = A + (size_t)(m0 + srow) * LDK + soff;
  const unsigned short* Bptr = BT + (size_t)(n0 + srow) * LDK + soff;
  const bool avalid = (MODE == 0) ? (m0 + srow < M) : true;
  const short8v z8 = {0, 0, 0, 0, 0, 0, 0, 0};

  for (int k0 = 0; k0 < LDK; k0 += 32) {
    short8v a0 = z8, a1 = z8;
    if (avalid) {
      a0 = *(const short8v*)(Aptr + k0);
      a1 = *(const short8v*)(Aptr + k0 + 8);
    }
    short8v b0 = *(const short8v*)(Bptr + k0);
    short8v b1 = *(const short8v*)(Bptr + k0 + 8);
    __syncthreads();
    *(short8v*)&As[srow * 40 + soff]     = a0;
    *(short8v*)&As[srow * 40 + soff + 8] = a1;
    *(short8v*)&Bs[srow * 40 + soff]     = b0;
    *(short8v*)&Bs[srow * 40 + soff + 8] = b1;
    __syncthreads();
    short8v af[4], bf[4];
#pragma unroll
    for (int mi = 0; mi < 4; ++mi)
      af[mi] = *(short8v*)&As[(wr * 64 + mi * 16 + lm16) * 40 + lg16 * 8];
#pragma unroll
    for (int ni = 0; ni < 4; ++ni)
      bf[ni] = *(short8v*)&Bs[(wc * 64 + ni * 16 + lm16) * 40 + lg16 * 8];
#pragma unroll
    for (int mi = 0; mi < 4; ++mi)
#pragma unroll
      for (int ni = 0; ni < 4; ++ni)
        acc[mi][ni] = __builtin_amdgcn_mfma_f32_16x16x32_bf16(
            af[mi], bf[ni], acc[mi][ni], 0, 0, 0);
  }

  if (MODE == 1) {
#pragma unroll
    for (int mi = 0; mi < 4; ++mi) {
      const int row0 = m0 + wr * 64 + mi * 16 + lg16 * 4;
#pragma unroll
      for (int ni = 0; ni < 4; ++ni) {
        const int col = n0 + wc * 64 + ni * 16 + lm16;
        const float bv = bias[col];
#pragma unroll
        for (int r = 0; r < 4; ++r)
          po[(size_t)(row0 + r) * 768 + col] = acc[mi][ni][r] + bv;
      }
    }
  } else {
#pragma unroll
    for (int mi = 0; mi < 4; ++mi) {
      const int row0 = m0 + wr * 64 + mi * 16 + lg16 * 4;
#pragma unroll
      for (int ni = 0; ni < 4; ++ni) {
        const int col = n0 + wc * 64 + ni * 16 + lm16;
        const int which = col / 768;
        const int rem = col - which * 768;
        const int head = rem >> 6, d = rem & 63;
        const float bv = bias[col];
#pragma unroll
        for (int r = 0; r < 4; ++r) {
          const int grow = row0 + r;
          if (grow >= M) continue;
          const int b = grow / 1025;
          const int n = grow - b * 1025;
          const unsigned short val = f2b(acc[mi][ni][r] + bv);
          if (which == 0)
            qo[((size_t)(b * NH + head) * N_ + n) * HD + d] = val;
          else if (which == 1)
            ko[((size_t)(b * NH + head) * KROWS + n) * HD + d] = val;
          else
            vo[((size_t)(b * NH + head) * HD + d) * NPAD + n] = val;
        }
      }
    }
  }
}

// ---------------- MFMA flash attention v4 ----------------
// 4 waves/block, wave owns 16 q rows. No in-loop barriers: K/V fragments
// direct from global (L2-resident via XCD swizzle), K prefetched 1 tile
// ahead in registers. Rel-pos bias prologue computed with MFMA.
__global__ __launch_bounds__(256) void attn_mfma(
    const unsigned short* __restrict__ qp, const unsigned short* __restrict__ kp,
    const unsigned short* __restrict__ vp, const float* __restrict__ mask_f,
    const float* __restrict__ rph, const float* __restrict__ rpw,
    unsigned short* __restrict__ ao)
{
  // bijective XCD swizzle: XCD x owns 12 (b,head) pairs x 16 q-tiles
  const int bid = blockIdx.x;
  const int work = (bid & 7) * 192 + (bid >> 3);
  const int qt = work & 15;
  const int bh = work >> 4;               // 0..95 = b*NH+head
  const int b = bh / NH, head = bh - b * NH;

  const int t = threadIdx.x, l = t & 63, w = t >> 6;
  const int lg16 = l >> 4, lm16 = l & 15;
  const int w16 = w * 16;
  constexpr float L2E = 1.44269504f;
  constexpr float SCL = 0.125f * L2E;
  constexpr float MCOL = -1.44269504e9f;  // -1e9 * log2e
  constexpr float THR_L = 5.77f;          // defer-max threshold (4 nats)

  __shared__ float bh_lds[64][33];        // [q][kh 0..32] * log2e, col32=0
  __shared__ float bw2_lds[64][48];       // [q][r], r = 31 + qloc - kw
  __shared__ float ct_lds[NPAD];          // column mask term * log2e
  __shared__ unsigned int p_lds[4][16 * 20];

  const unsigned short* qb = qp + (size_t)bh * N_ * HD;
  const unsigned short* kb = kp + (size_t)bh * KROWS * HD;
  const unsigned short* vb = vp + (size_t)bh * HD * NPAD;
  const int q0 = qt * 64 + w16;

  // ---- column term fill ----
  for (int i = t; i < NPAD; i += 256)
    ct_lds[i] = (i < N_) ? (MCOL * (1.f - mask_f[b * N_ + i])) : -2e30f;

  // ---- Q fragments (B operand): col=lm16=q, k(d)=kk*32+lg16*8+j ----
  short8v qf[2];
#pragma unroll
  for (int kk = 0; kk < 2; ++kk)
    qf[kk] = *(const short8v*)&qb[(size_t)(1 + q0 + lm16) * HD + kk * 32 + lg16 * 8];

  // ---- rel-pos bias tables via MFMA (swapped layout, same as QK^T) ----
  // bh[q][kh] = Q[q]·Rh[hq-kh+31]; bw'[q][r] = Q[q]·Rw[wq0+r], r=31+qloc-kw
  {
    const int hq = q0 >> 5, wq0 = q0 & 31;
    const f32x4 z4 = (f32x4){0.f, 0.f, 0.f, 0.f};
    f32x4 sbh[2] = {z4, z4};
    f32x4 sbw[3] = {z4, z4, z4};
#pragma unroll
    for (int nt = 0; nt < 2; ++nt) {
      const float* rp = &rph[(size_t)(hq + 31 - (nt * 16 + lm16)) * HD];
#pragma unroll
      for (int kk = 0; kk < 2; ++kk) {
        float4 lo = *(const float4*)&rp[kk * 32 + lg16 * 8];
        float4 hi = *(const float4*)&rp[kk * 32 + lg16 * 8 + 4];
        sbh[nt] = __builtin_amdgcn_mfma_f32_16x16x32_bf16(
            pack8(lo, hi), qf[kk], sbh[nt], 0, 0, 0);
      }
    }
#pragma unroll
    for (int nt = 0; nt < 3; ++nt) {
      int u = wq0 + nt * 16 + lm16;
      u = u > 62 ? 62 : u;
      const float* rp = &rpw[(size_t)u * HD];
#pragma unroll
      for (int kk = 0; kk < 2; ++kk) {
        float4 lo = *(const float4*)&rp[kk * 32 + lg16 * 8];
        float4 hi = *(const float4*)&rp[kk * 32 + lg16 * 8 + 4];
        sbw[nt] = __builtin_amdgcn_mfma_f32_16x16x32_bf16(
            pack8(lo, hi), qf[kk], sbw[nt], 0, 0, 0);
      }
    }
    // C layout: col=lm16=q, row=lg16*4+reg (+16nt)
#pragma unroll
    for (int nt = 0; nt < 2; ++nt)
#pragma unroll
      for (int reg = 0; reg < 4; ++reg)
        bh_lds[w16 + lm16][nt * 16 + lg16 * 4 + reg] = sbh[nt][reg] * L2E;
    if (lg16 == 0) bh_lds[w16 + lm16][32] = 0.f;
#pragma unroll
    for (int nt = 0; nt < 3; ++nt)
#pragma unroll
      for (int reg = 0; reg < 4; ++reg)
        bw2_lds[w16 + lm16][nt * 16 + lg16 * 4 + reg] = sbw[nt][reg] * L2E;
  }
  __syncthreads();

  // ---- per-lane preloads ----
  const float mi_s = mask_f[b * N_ + 1 + q0 + lm16];
  const bool mzero = (mi_s == 0.f);
  float bwv[2][4];
#pragma unroll
  for (int nt = 0; nt < 2; ++nt)
#pragma unroll
    for (int reg = 0; reg < 4; ++reg) {
      const int kw = (lg16 * 4 + reg + 16 * nt + 31) & 31;
      bwv[nt][reg] = bw2_lds[w16 + lm16][31 + lm16 - kw];
    }
  const float bw31v = bw2_lds[w16 + lm16][lm16];   // kw=31 -> r=qloc

  float m_lm = -1e30f, l_lm = 0.f, bh_prev = 0.f;
  f32x4 oacc[4];
#pragma unroll
  for (int dt = 0; dt < 4; ++dt) oacc[dt] = (f32x4){0.f, 0.f, 0.f, 0.f};
  unsigned int* pw = &p_lds[w][lm16 * 20 + lg16 * 2];
  const unsigned int* pr = &p_lds[w][lm16 * 20 + lg16 * 4];

  // ---- K register prefetch for tile 0 ----
  short8v kfn[2][2];
#pragma unroll
  for (int nt = 0; nt < 2; ++nt)
#pragma unroll
    for (int kk = 0; kk < 2; ++kk)
      kfn[nt][kk] = *(const short8v*)
          &kb[(size_t)(nt * 16 + lm16) * HD + kk * 32 + lg16 * 8];

  for (int kt = 0; kt < 33; ++kt) {
    const int kv0 = kt * 32;
    short8v kf[2][2];
#pragma unroll
    for (int nt = 0; nt < 2; ++nt)
#pragma unroll
      for (int kk = 0; kk < 2; ++kk) kf[nt][kk] = kfn[nt][kk];
    const int nkv0 = (kt < 32) ? kv0 + 32 : kv0;
#pragma unroll
    for (int nt = 0; nt < 2; ++nt)
#pragma unroll
      for (int kk = 0; kk < 2; ++kk)
        kfn[nt][kk] = *(const short8v*)
            &kb[(size_t)(nkv0 + nt * 16 + lm16) * HD + kk * 32 + lg16 * 8];
    short8v vf[4];
#pragma unroll
    for (int dt = 0; dt < 4; ++dt)
      vf[dt] = *(const short8v*)
          &vb[(size_t)(dt * 16 + lm16) * NPAD + kv0 + lg16 * 8];

    // ---- S^T = mfma(K, Q): lane holds q=lm16, kv=(lg16*4+reg)+16nt ----
    f32x4 s[2];
#pragma unroll
    for (int nt = 0; nt < 2; ++nt) {
      f32x4 sa = (f32x4){0.f, 0.f, 0.f, 0.f};
      sa = __builtin_amdgcn_mfma_f32_16x16x32_bf16(kf[nt][0], qf[0], sa, 0, 0, 0);
      sa = __builtin_amdgcn_mfma_f32_16x16x32_bf16(kf[nt][1], qf[1], sa, 0, 0, 0);
      s[nt] = sa;
    }
    // ---- logits (log2 domain) ----
    const float bh_k = bh_lds[w16 + lm16][kt];
    const float edgebias = (kt == 0) ? 0.f : (bh_prev + bw31v);
    bh_prev = bh_k;
    f32x4 ct4[2];
#pragma unroll
    for (int nt = 0; nt < 2; ++nt)
      ct4[nt] = *(const f32x4*)&ct_lds[kv0 + nt * 16 + lg16 * 4];
    float lg_[2][4];
#pragma unroll
    for (int nt = 0; nt < 2; ++nt)
#pragma unroll
      for (int reg = 0; reg < 4; ++reg) {
        float bias2 = bh_k + bwv[nt][reg];
        if (nt == 0 && reg == 0) bias2 = (lg16 == 0) ? edgebias : bias2;
        const float ctv = ct4[nt][reg];
        const float ec = mzero ? fminf(ctv, MCOL) : ctv;
        lg_[nt][reg] = fmaf(SCL, s[nt][reg], bias2 + ec);
      }
    // ---- online softmax with defer-max ----
    float tm = fmaxf(fmaxf(fmaxf(lg_[0][0], lg_[0][1]), fmaxf(lg_[0][2], lg_[0][3])),
                     fmaxf(fmaxf(lg_[1][0], lg_[1][1]), fmaxf(lg_[1][2], lg_[1][3])));
    tm = fmaxf(tm, __shfl_xor(tm, 16));
    tm = fmaxf(tm, __shfl_xor(tm, 32));
    if (__any(tm > m_lm + THR_L)) {
      const float nm = fmaxf(m_lm, tm);
      const float rf = exp2f(m_lm - nm);
      m_lm = nm;
      l_lm *= rf;
      float rfr[4];
#pragma unroll
      for (int reg = 0; reg < 4; ++reg) rfr[reg] = __shfl(rf, lg16 * 4 + reg);
#pragma unroll
      for (int dt = 0; dt < 4; ++dt)
#pragma unroll
        for (int reg = 0; reg < 4; ++reg) oacc[dt][reg] *= rfr[reg];
    }
    float p[2][4], ps = 0.f;
#pragma unroll
    for (int nt = 0; nt < 2; ++nt)
#pragma unroll
      for (int reg = 0; reg < 4; ++reg) {
        p[nt][reg] = exp2f(lg_[nt][reg] - m_lm);
        ps += p[nt][reg];
      }
    ps += __shfl_xor(ps, 16);
    ps += __shfl_xor(ps, 32);
    l_lm += ps;
    // ---- P -> bf16 -> per-wave LDS -> PV A-fragment ----
    pw[0] = cvtpk(p[0][0], p[0][1]);
    pw[1] = cvtpk(p[0][2], p[0][3]);
    pw[8] = cvtpk(p[1][0], p[1][1]);
    pw[9] = cvtpk(p[1][2], p[1][3]);
    const short8v pa = *(const short8v*)pr;
#pragma unroll
    for (int dt = 0; dt < 4; ++dt)
      oacc[dt] = __builtin_amdgcn_mfma_f32_16x16x32_bf16(
          pa, vf[dt], oacc[dt], 0, 0, 0);
  }

  // ---- epilogue ----
  float inv[4];
#pragma unroll
  for (int reg = 0; reg < 4; ++reg)
    inv[reg] = 1.f / __shfl(l_lm, lg16 * 4 + reg);
#pragma unroll
  for (int dt = 0; dt < 4; ++dt)
#pragma unroll
    for (int reg = 0; reg < 4; ++reg) {
      const int nsp = q0 + lg16 * 4 + reg;
      const float val = oacc[dt][reg] * inv[reg];
      ao[((size_t)(b * NSP + nsp)) * DIM + head * HD + dt * 16 + lm16] = f2b(val);
    }
}

// ---------------- two-stage masked avg + max pooling ----------------
__global__ __launch_bounds__(256) void pool_stage1(
    const float* __restrict__ po, const float* __restrict__ mask_f,
    float* __restrict__ psum, float* __restrict__ pmax, float* __restrict__ pcnt)
{
  const int b = blockIdx.y, z = blockIdx.z, cx = blockIdx.x;
  const int c = cx * 256 + threadIdx.x;
  const int n0 = z * 128;
  float sum = 0.f, mx = -3.402823466e+38f;
  for (int n = n0; n < n0 + 128; ++n) {
    const float m = mask_f[b * N_ + 1 + n];
    const float v = po[((size_t)(b * NSP + n)) * DIM + c];
    sum = fmaf(v, m, sum);
    mx = fmaxf(mx, v);
  }
  psum[(z * 8 + b) * 768 + c] = sum;
  pmax[(z * 8 + b) * 768 + c] = mx;
  if (cx == 0 && threadIdx.x < 128)
    atomicAdd(&pcnt[z * 8 + b], mask_f[b * N_ + 1 + n0 + threadIdx.x]);
}

__global__ __launch_bounds__(256) void pool_stage2(
    const float* __restrict__ psum, const float* __restrict__ pmax,
    const float* __restrict__ pcnt, float* __restrict__ out)
{
  const int b = blockIdx.y;
  const int c = blockIdx.x * 256 + threadIdx.x;
  float s = 0.f, mx = -3.402823466e+38f, cnt = 0.f;
#pragma unroll
  for (int z = 0; z < 8; ++z) {
    s  += psum[(z * 8 + b) * 768 + c];
    mx  = fmaxf(mx, pmax[(z * 8 + b) * 768 + c]);
    cnt += pcnt[z * 8 + b];
  }
  out[b * 1536 + c]       = s / (cnt + 1e-7f);
  out[b * 1536 + 768 + c] = mx;
}

// ---------------- launch ----------------
extern "C" void kernel_launch(void* const* d_in, const int* in_sizes, int n_in,
                              void* d_out, int out_size, void* d_ws, size_t ws_size,
                              hipStream_t stream) {
  const float* x      = (const float*)d_in[0];
  const unsigned char* mraw = (const unsigned char*)d_in[1];
  const float* qkv_w  = (const float*)d_in[2];
  const float* qkv_b  = (const float*)d_in[3];
  const float* proj_w = (const float*)d_in[4];
  const float* proj_b = (const float*)d_in[5];
  const float* rph    = (const float*)d_in[6];
  const float* rpw    = (const float*)d_in[7];

  char* ws = (char*)d_ws;
  float*          mask_f = (float*)(ws + OFF_MASK);
  unsigned short* xb     = (unsigned short*)(ws + OFF_XB);
  unsigned short* qkvwT  = (unsigned short*)(ws + OFF_QKVWT);
  unsigned short* projwT = (unsigned short*)(ws + OFF_PROJWT);
  unsigned short* qW     = (unsigned short*)(ws + OFF_Q);
  unsigned short* kW     = (unsigned short*)(ws + OFF_K);
  unsigned short* vW     = (unsigned short*)(ws + OFF_V);
  unsigned short* aoW    = (unsigned short*)(ws + OFF_AO);
  float*          po     = (float*)(ws + OFF_PO);
  float*          psum   = (float*)(ws + OFF_PS);
  float*          pmax   = (float*)(ws + OFF_PM);
  float*          pcnt   = (float*)(ws + OFF_PC);

  mask_convert<<<1, 256, 0, stream>>>(mraw, mask_f, B_ * N_);
  cvt_f32_bf16<<<2048, 256, 0, stream>>>(x, xb, 8200 * 768 / 4);
  transpose_cvt<<<dim3(K3 / 32, 768 / 32), dim3(32, 32), 0, stream>>>(
      qkv_w, qkvwT, 768, K3);
  transpose_cvt<<<dim3(768 / 32, 768 / 32), dim3(32, 32), 0, stream>>>(
      proj_w, projwT, 768, 768);
  pad_zero<<<96, 256, 0, stream>>>(kW, vW);

  gemm_bf16<0><<<dim3(K3 / 128, 65), 256, 0, stream>>>(
      xb, qkvwT, qkv_b, qW, kW, vW, nullptr, 8200);

  attn_mfma<<<1536, 256, 0, stream>>>(
      qW, kW, vW, mask_f, rph, rpw, aoW);

  gemm_bf16<1><<<dim3(768 / 128, 64), 256, 0, stream>>>(
      aoW, projwT, proj_b, nullptr, nullptr, nullptr, po, 8192);

  hipMemsetAsync(pcnt, 0, 64 * 4, stream);
  pool_stage1<<<dim3(3, B_, 8), 256, 0, stream>>>(po, mask_f, psum, pmax, pcnt);
  pool_stage2<<<dim3(3, B_), 256, 0, stream>>>(psum, pmax, pcnt, (float*)d_out);
}